// Round 1
// baseline (879.109 us; speedup 1.0000x reference)
//
#include <hip/hip_runtime.h>
#include <math.h>

// ---------------- problem constants ----------------
// B=2, K=19 -> BK=38 batches; M=1024 points; C=256 feat ch; NPOINT=NSAMPLE=128
#define NBK   38
#define NPTS  1024

// ---------------- workspace layout (bytes) ----------------
#define OFF_XC    0u          // [38][3][1024] f32        = 466944
#define OFF_NXYZ  466944u     // [38][128][3]  f32        = 58368
#define OFF_BIDX  525312u     // [38][128][128] i32       = 2490368
#define OFF_W1F   3015680u    // [38][1024][128] f32      = 19922944
#define OFF_PREP  22938624u   // 4096 f32 (alpha/beta/packed-consts)
#define OFF_WT    22955008u   // 98304 f32: w2t,w3t,c1t,c2t,w1t

// ---------------- d_out layout (float offsets) ----------------
#define OUT_AGG   24320       // scores at 0: (2,19,128,5)
#define OUT_FEAT  38912       // agg: (2,19,128,3), feat: (2,19,128,128)

// exact IEEE fp32 squared distance, no FMA contraction, ((d0^2+d1^2)+d2^2)
__device__ __forceinline__ float dist2f(float a0, float a1, float a2,
                                        float b0, float b1, float b2) {
#pragma clang fp contract(off)
  float d0 = a0 - b0;
  float d1 = a1 - b1;
  float d2 = a2 - b2;
  return d0 * d0 + d1 * d1 + d2 * d2;
}

// ---------------- prep: fold BN, transpose weights ----------------
__global__ __launch_bounds__(256) void prep_kernel(
    const float* __restrict__ m1w, const float* __restrict__ m1g, const float* __restrict__ m1be,
    const float* __restrict__ m2w, const float* __restrict__ m2b, const float* __restrict__ m2g, const float* __restrict__ m2be,
    const float* __restrict__ m3w, const float* __restrict__ m3b, const float* __restrict__ m3g, const float* __restrict__ m3be,
    const float* __restrict__ c1w, const float* __restrict__ c1b, const float* __restrict__ c1g, const float* __restrict__ c1be,
    const float* __restrict__ c2w, const float* __restrict__ c2b, const float* __restrict__ c2g, const float* __restrict__ c2be,
    float* __restrict__ prep, float* __restrict__ wt)
{
  int t = threadIdx.x;
  float inv = 1.0f / sqrtf(1.0f + 1e-5f);
  if (t < 128) {
    float a1 = m1g[t] * inv;
    prep[t] = a1;                      // alpha1 (used by w1f_kernel prescale)
    prep[128 + t] = m1be[t];
    float a2 = m2g[t] * inv;  prep[256 + t] = a2;  prep[384 + t] = fmaf(m2b[t], a2, m2be[t]);
    float a3 = m3g[t] * inv;  prep[512 + t] = a3;  prep[640 + t] = fmaf(m3b[t], a3, m3be[t]);
    float ac1 = c1g[t] * inv; prep[768 + t] = ac1; prep[896 + t] = fmaf(c1b[t], ac1, c1be[t]);
    float ac2 = c2g[t] * inv; prep[1024 + t] = ac2; prep[1152 + t] = fmaf(c2b[t], ac2, c2be[t]);
    // packed per-channel consts for h1 build: {wx0*a1, wx1*a1, wx2*a1, be1}
    prep[1280 + 4 * t + 0] = m1w[t * 259 + 0] * a1;
    prep[1280 + 4 * t + 1] = m1w[t * 259 + 1] * a1;
    prep[1280 + 4 * t + 2] = m1w[t * 259 + 2] * a1;
    prep[1280 + 4 * t + 3] = m1be[t];
  }
  for (int i = t; i < 16384; i += 256) {
    int c = i >> 7, o = i & 127;
    wt[i]          = m2w[o * 128 + c];   // w2t[c][o]
    wt[16384 + i]  = m3w[o * 128 + c];   // w3t[c][o]
    wt[32768 + i]  = c1w[o * 128 + c];   // c1t[c][o]
    wt[49152 + i]  = c2w[o * 128 + c];   // c2t[c][o]
  }
  for (int i = t; i < 32768; i += 256) {
    int c = i >> 7, o = i & 127;
    wt[65536 + i] = m1w[o * 259 + 3 + c]; // w1t[c][o] (feature part)
  }
}

// ---------------- FPS: one wave per batch, bit-exact vs reference ----------------
__global__ __launch_bounds__(64) void fps_kernel(const float* __restrict__ xyz,
    float* __restrict__ xc, float* __restrict__ nxyz, float* __restrict__ agg)
{
  int bk = blockIdx.x, lane = threadIdx.x;
  int b = bk / 19, k = bk % 19;
  __shared__ float sx0[1024], sx1[1024], sx2[1024];
  for (int i = lane; i < 1024; i += 64) {
    const float* src = xyz + ((size_t)((b * 1024 + i) * 19 + k)) * 3;
    float v0 = src[0], v1 = src[1], v2 = src[2];
    sx0[i] = v0; sx1[i] = v1; sx2[i] = v2;
    xc[(bk * 3 + 0) * 1024 + i] = v0;
    xc[(bk * 3 + 1) * 1024 + i] = v1;
    xc[(bk * 3 + 2) * 1024 + i] = v2;
  }
  __syncthreads();
  float dist[16];
#pragma unroll
  for (int j = 0; j < 16; ++j) dist[j] = 1e10f;
  int far = 0;
  for (int t = 0; t < 128; ++t) {
    float c0 = sx0[far], c1 = sx1[far], c2 = sx2[far];
    if (lane < 3) {
      float cv = (lane == 0) ? c0 : ((lane == 1) ? c1 : c2);
      nxyz[(bk * 128 + t) * 3 + lane] = cv;
      agg[(bk * 128 + t) * 3 + lane]  = cv;
    }
    unsigned long long best = 0ull;
#pragma unroll
    for (int j = 0; j < 16; ++j) {
      int m = j * 64 + lane;
      float d = dist2f(sx0[m], sx1[m], sx2[m], c0, c1, c2);
      float dj = fminf(dist[j], d);
      dist[j] = dj;
      // max dist wins; ties -> smallest index (matches jnp.argmax first-max)
      unsigned long long key =
          ((unsigned long long)__float_as_uint(dj) << 32) | (unsigned)(1023 - m);
      if (key > best) best = key;
    }
#pragma unroll
    for (int off = 32; off > 0; off >>= 1) {
      unsigned hi = (unsigned)(best >> 32), lo = (unsigned)(best & 0xffffffffu);
      unsigned h2 = __shfl_xor(hi, off);
      unsigned l2 = __shfl_xor(lo, off);
      unsigned long long ob = ((unsigned long long)h2 << 32) | l2;
      if (ob > best) best = ob;
    }
    far = 1023 - (int)(best & 0xffffffffu);
  }
}

// ---------------- ball query: one wave per (bk,p) ----------------
__global__ __launch_bounds__(64) void ball_kernel(const float* __restrict__ xc,
    const float* __restrict__ nxyz, int* __restrict__ bidx)
{
  int gb = blockIdx.x;
  int bk = gb >> 7, p = gb & 127, lane = threadIdx.x;
  const float* x0 = xc + (bk * 3 + 0) * 1024;
  const float* x1 = xc + (bk * 3 + 1) * 1024;
  const float* x2 = xc + (bk * 3 + 2) * 1024;
  float c0 = nxyz[(bk * 128 + p) * 3 + 0];
  float c1 = nxyz[(bk * 128 + p) * 3 + 1];
  float c2 = nxyz[(bk * 128 + p) * 3 + 2];
  int* out = bidx + ((size_t)gb) * 128;
  int count = 0, first = 0;
  bool got = false;
  for (int ch = 0; ch < 16 && count < 128; ++ch) {
    int m = (ch << 6) + lane;
    float d = dist2f(x0[m], x1[m], x2[m], c0, c1, c2);
    bool flag = d < 0.0225f;                 // strict fp32 compare, RADIUS^2
    unsigned long long mask = __ballot(flag);
    if (!got && mask) { first = (ch << 6) + __builtin_ctzll(mask); got = true; }
    int pos = count + (int)__popcll(mask & ((1ull << lane) - 1ull));
    if (flag && pos < 128) out[pos] = m;
    count += (int)__popcll(mask);
  }
  for (int j = count + lane; j < 128; j += 64) out[j] = first;
}

// ---------------- W1f: per-point layer-1 feature GEMM (prescaled by alpha1) ----------------
__global__ __launch_bounds__(256) void w1f_kernel(const float* __restrict__ feats,
    const float* __restrict__ m1b, const float* __restrict__ prep,
    const float* __restrict__ wt, float* __restrict__ W1f)
{
  int blk = blockIdx.x;
  int bk = blk >> 5;
  int m0 = (blk & 31) << 5;
  int b = bk / 19, k = bk % 19;
  int t = threadIdx.x;
  int o = t & 127, mg = t >> 7;
  __shared__ __align__(16) float sf[8][32];
  const float* w1t = wt + 65536;
  float acc[16];
#pragma unroll
  for (int j = 0; j < 16; ++j) acc[j] = 0.f;
  for (int cc = 0; cc < 256; cc += 8) {
    __syncthreads();
    {
      int c = t >> 5, mm = t & 31;
      sf[c][mm] = feats[((size_t)((b * 256 + cc + c) * 19 + k)) * 1024 + m0 + mm];
    }
    __syncthreads();
#pragma unroll
    for (int c = 0; c < 8; ++c) {
      float wv = w1t[(cc + c) * 128 + o];
      const float4* sp = (const float4*)&sf[c][mg * 16];
      float4 f0 = sp[0], f1 = sp[1], f2 = sp[2], f3 = sp[3];
      acc[0]  = fmaf(wv, f0.x, acc[0]);  acc[1]  = fmaf(wv, f0.y, acc[1]);
      acc[2]  = fmaf(wv, f0.z, acc[2]);  acc[3]  = fmaf(wv, f0.w, acc[3]);
      acc[4]  = fmaf(wv, f1.x, acc[4]);  acc[5]  = fmaf(wv, f1.y, acc[5]);
      acc[6]  = fmaf(wv, f1.z, acc[6]);  acc[7]  = fmaf(wv, f1.w, acc[7]);
      acc[8]  = fmaf(wv, f2.x, acc[8]);  acc[9]  = fmaf(wv, f2.y, acc[9]);
      acc[10] = fmaf(wv, f2.z, acc[10]); acc[11] = fmaf(wv, f2.w, acc[11]);
      acc[12] = fmaf(wv, f3.x, acc[12]); acc[13] = fmaf(wv, f3.y, acc[13]);
      acc[14] = fmaf(wv, f3.z, acc[14]); acc[15] = fmaf(wv, f3.w, acc[15]);
    }
  }
  float bb = m1b[o], al = prep[o];
#pragma unroll
  for (int j = 0; j < 16; ++j) {
    int m = m0 + mg * 16 + j;
    W1f[((size_t)(bk * 1024 + m)) * 128 + o] = (acc[j] + bb) * al;
  }
}

// 8x8 register-tile GEMM over a 128x128 LDS operand; w is [c][o] in global
__device__ __forceinline__ void gemm_tile(const float* __restrict__ w,
                                          const float* lds, int tx, int ty,
                                          float acc[8][8])
{
#pragma unroll
  for (int i = 0; i < 8; ++i)
#pragma unroll
    for (int j = 0; j < 8; ++j) acc[i][j] = 0.f;
  for (int c = 0; c < 128; ++c) {
    const float4* wr = (const float4*)(w + c * 128 + ty * 8);
    float4 a0 = wr[0], a1 = wr[1];
    const float4* hr = (const float4*)(lds + c * 128 + tx * 8);
    float4 b0 = hr[0], b1 = hr[1];
    float av[8] = {a0.x, a0.y, a0.z, a0.w, a1.x, a1.y, a1.z, a1.w};
    float bv[8] = {b0.x, b0.y, b0.z, b0.w, b1.x, b1.y, b1.z, b1.w};
#pragma unroll
    for (int i = 0; i < 8; ++i)
#pragma unroll
      for (int j = 0; j < 8; ++j) acc[i][j] = fmaf(av[i], bv[j], acc[i][j]);
  }
}

// ---------------- fused SA: h1 build -> layer2 -> layer3 -> max over samples ----------------
__global__ __launch_bounds__(256) void sa_kernel(
    const float* __restrict__ xc, const float* __restrict__ nxyz,
    const int* __restrict__ bidx, const float* __restrict__ W1f,
    const float* __restrict__ prep, const float* __restrict__ wt,
    float* __restrict__ feat_out)
{
  __shared__ __align__(16) float hbuf[128 * 128];   // 64 KB, reused for h1/h2/smax
  int gb = blockIdx.x;
  int bk = gb >> 7, p = gb & 127;
  int t = threadIdx.x;

  // ---- h1 build: h1[c][s] = relu(W1f_scaled[m][c] + pc[c].xyz . gxn + pc[c].w)
  {
    int s = t & 127;
    int ch0 = (t >> 7) << 6;                        // 0 or 64
    int m = bidx[((size_t)gb) * 128 + s];
    float cen0 = nxyz[(bk * 128 + p) * 3 + 0];
    float cen1 = nxyz[(bk * 128 + p) * 3 + 1];
    float cen2 = nxyz[(bk * 128 + p) * 3 + 2];
    float g0 = (xc[(bk * 3 + 0) * 1024 + m] - cen0) / 0.15f;
    float g1 = (xc[(bk * 3 + 1) * 1024 + m] - cen1) / 0.15f;
    float g2 = (xc[(bk * 3 + 2) * 1024 + m] - cen2) / 0.15f;
    const float4* wrow = (const float4*)(W1f + ((size_t)(bk * 1024 + m)) * 128 + ch0);
    const float4* pcp = (const float4*)(prep + 1280);
#pragma unroll
    for (int j = 0; j < 16; ++j) {
      float4 wv = wrow[j];
      int c = ch0 + j * 4;
      float4 p0 = pcp[c + 0], p1 = pcp[c + 1], p2 = pcp[c + 2], p3 = pcp[c + 3];
      hbuf[(c + 0) * 128 + s] = fmaxf(wv.x + p0.x * g0 + p0.y * g1 + p0.z * g2 + p0.w, 0.f);
      hbuf[(c + 1) * 128 + s] = fmaxf(wv.y + p1.x * g0 + p1.y * g1 + p1.z * g2 + p1.w, 0.f);
      hbuf[(c + 2) * 128 + s] = fmaxf(wv.z + p2.x * g0 + p2.y * g1 + p2.z * g2 + p2.w, 0.f);
      hbuf[(c + 3) * 128 + s] = fmaxf(wv.w + p3.x * g0 + p3.y * g1 + p3.z * g2 + p3.w, 0.f);
    }
  }
  __syncthreads();

  int tx = t & 15, ty = t >> 4;
  float acc[8][8];

  // ---- layer 2
  gemm_tile(wt, hbuf, tx, ty, acc);
  __syncthreads();                                   // all h1 reads complete
#pragma unroll
  for (int i = 0; i < 8; ++i) {
    int o = ty * 8 + i;
    float al = prep[256 + o], be = prep[384 + o];
    float4 v0, v1;
    v0.x = fmaxf(fmaf(acc[i][0], al, be), 0.f);
    v0.y = fmaxf(fmaf(acc[i][1], al, be), 0.f);
    v0.z = fmaxf(fmaf(acc[i][2], al, be), 0.f);
    v0.w = fmaxf(fmaf(acc[i][3], al, be), 0.f);
    v1.x = fmaxf(fmaf(acc[i][4], al, be), 0.f);
    v1.y = fmaxf(fmaf(acc[i][5], al, be), 0.f);
    v1.z = fmaxf(fmaf(acc[i][6], al, be), 0.f);
    v1.w = fmaxf(fmaf(acc[i][7], al, be), 0.f);
    *(float4*)(hbuf + o * 128 + tx * 8)     = v0;
    *(float4*)(hbuf + o * 128 + tx * 8 + 4) = v1;
  }
  __syncthreads();

  // ---- layer 3 + max over samples
  gemm_tile(wt + 16384, hbuf, tx, ty, acc);
  __syncthreads();                                   // all h2 reads complete
  float* smax = hbuf;                                // alias (stride 17 to dodge conflicts)
#pragma unroll
  for (int i = 0; i < 8; ++i) {
    int o = ty * 8 + i;
    float al = prep[512 + o], be = prep[640 + o];
    float mv = fmaxf(fmaf(acc[i][0], al, be), 0.f);
#pragma unroll
    for (int j = 1; j < 8; ++j) mv = fmaxf(mv, fmaxf(fmaf(acc[i][j], al, be), 0.f));
    smax[o * 17 + tx] = mv;
  }
  __syncthreads();
  if (t < 128) {
    float mm = smax[t * 17];
#pragma unroll
    for (int q = 1; q < 16; ++q) mm = fmaxf(mm, smax[t * 17 + q]);
    feat_out[((size_t)bk << 14) + (t << 7) + p] = mm;
  }
}

// ---------------- head: c1 -> c2 -> op -> scores ----------------
__global__ __launch_bounds__(256) void head_kernel(const float* __restrict__ featg,
    const float* __restrict__ prep, const float* __restrict__ wt,
    const float* __restrict__ nxyz, const float* __restrict__ opw,
    const float* __restrict__ opb, float* __restrict__ scores)
{
  __shared__ __align__(16) float buf[128 * 128];
  int bk = blockIdx.x, t = threadIdx.x;
  for (int i = t; i < 16384; i += 256) buf[i] = featg[(bk << 14) + i];
  __syncthreads();
  int tx = t & 15, ty = t >> 4;
  float acc[8][8];

  // c1
  gemm_tile(wt + 32768, buf, tx, ty, acc);
  __syncthreads();
#pragma unroll
  for (int i = 0; i < 8; ++i) {
    int o = ty * 8 + i;
    float al = prep[768 + o], be = prep[896 + o];
#pragma unroll
    for (int j = 0; j < 8; ++j)
      buf[o * 128 + tx * 8 + j] = fmaxf(fmaf(acc[i][j], al, be), 0.f);
  }
  __syncthreads();

  // c2
  gemm_tile(wt + 49152, buf, tx, ty, acc);
  __syncthreads();
#pragma unroll
  for (int i = 0; i < 8; ++i) {
    int o = ty * 8 + i;
    float al = prep[1024 + o], be = prep[1152 + o];
#pragma unroll
    for (int j = 0; j < 8; ++j)
      buf[o * 128 + tx * 8 + j] = fmaxf(fmaf(acc[i][j], al, be), 0.f);
  }
  __syncthreads();

  // op head + scores assembly
  if (t < 128) {
    int p = t, k = bk % 19;
    float res[5];
#pragma unroll
    for (int j = 0; j < 5; ++j) {
      const float* wr = opw + ((size_t)(k * 5 + j)) * 128;
      float a = opb[k * 5 + j];
      for (int c = 0; c < 128; ++c) a = fmaf(wr[c], buf[c * 128 + p], a);
      res[j] = a;
    }
    float a0 = nxyz[(bk * 128 + p) * 3 + 0];
    float a1 = nxyz[(bk * 128 + p) * 3 + 1];
    float a2 = nxyz[(bk * 128 + p) * 3 + 2];
    float* sc = scores + ((size_t)(bk * 128 + p)) * 5;
    sc[0] = res[0];
    sc[1] = res[1];
    sc[2] = a0 + res[2];
    sc[3] = a1 + res[3];
    sc[4] = a2 + res[4];
  }
}

extern "C" void kernel_launch(void* const* d_in, const int* in_sizes, int n_in,
                              void* d_out, int out_size, void* d_ws, size_t ws_size,
                              hipStream_t stream) {
  (void)in_sizes; (void)n_in; (void)out_size; (void)ws_size;
  const float* xyz  = (const float*)d_in[0];
  const float* fts  = (const float*)d_in[1];
  const float* m1w  = (const float*)d_in[2];
  const float* m1b  = (const float*)d_in[3];
  const float* m1g  = (const float*)d_in[4];
  const float* m1be = (const float*)d_in[5];
  const float* m2w  = (const float*)d_in[6];
  const float* m2b  = (const float*)d_in[7];
  const float* m2g  = (const float*)d_in[8];
  const float* m2be = (const float*)d_in[9];
  const float* m3w  = (const float*)d_in[10];
  const float* m3b  = (const float*)d_in[11];
  const float* m3g  = (const float*)d_in[12];
  const float* m3be = (const float*)d_in[13];
  const float* c1w  = (const float*)d_in[14];
  const float* c1b  = (const float*)d_in[15];
  const float* c1g  = (const float*)d_in[16];
  const float* c1be = (const float*)d_in[17];
  const float* c2w  = (const float*)d_in[18];
  const float* c2b  = (const float*)d_in[19];
  const float* c2g  = (const float*)d_in[20];
  const float* c2be = (const float*)d_in[21];
  const float* opw  = (const float*)d_in[22];
  const float* opb  = (const float*)d_in[23];

  float* out = (float*)d_out;
  char* ws = (char*)d_ws;
  float* xc   = (float*)(ws + OFF_XC);
  float* nxyz = (float*)(ws + OFF_NXYZ);
  int*   bidx = (int*)(ws + OFF_BIDX);
  float* W1f  = (float*)(ws + OFF_W1F);
  float* prep = (float*)(ws + OFF_PREP);
  float* wt   = (float*)(ws + OFF_WT);

  hipLaunchKernelGGL(prep_kernel, dim3(1), dim3(256), 0, stream,
                     m1w, m1g, m1be, m2w, m2b, m2g, m2be, m3w, m3b, m3g, m3be,
                     c1w, c1b, c1g, c1be, c2w, c2b, c2g, c2be, prep, wt);
  hipLaunchKernelGGL(fps_kernel, dim3(NBK), dim3(64), 0, stream,
                     xyz, xc, nxyz, out + OUT_AGG);
  hipLaunchKernelGGL(ball_kernel, dim3(NBK * 128), dim3(64), 0, stream,
                     xc, nxyz, bidx);
  hipLaunchKernelGGL(w1f_kernel, dim3(NBK * 32), dim3(256), 0, stream,
                     fts, m1b, prep, wt, W1f);
  hipLaunchKernelGGL(sa_kernel, dim3(NBK * 128), dim3(256), 0, stream,
                     xc, nxyz, bidx, W1f, prep, wt, out + OUT_FEAT);
  hipLaunchKernelGGL(head_kernel, dim3(NBK), dim3(256), 0, stream,
                     out + OUT_FEAT, prep, wt, nxyz, opw, opb, out);
}

// Round 2
// 553.508 us; speedup vs baseline: 1.5883x; 1.5883x over previous
//
#include <hip/hip_runtime.h>
#include <math.h>

// ---------------- problem constants ----------------
// B=2, K=19 -> BK=38 batches; M=1024 points; C=256 feat ch; NPOINT=NSAMPLE=128
#define NBK   38
#define NPTS  1024

// ---------------- workspace layout (bytes) ----------------
#define OFF_XC    0u          // [38][3][1024] f32        = 466944
#define OFF_NXYZ  466944u     // [38][128][3]  f32        = 58368
#define OFF_BIDX  525312u     // [38][128][128] i32       = 2490368
#define OFF_W1F   3015680u    // [38][1024][128] f32      = 19922944
#define OFF_PREP  22938624u   // 4096 f32 (alpha/beta/packed-consts)
#define OFF_WT    22955008u   // 98304 f32: (unused)x2,c1t,c2t,w1t
#define OFF_WF    23348224u   // 98304 bf16 shorts: pre-split MFMA A-frags (192KB)

// ---------------- d_out layout (float offsets) ----------------
#define OUT_AGG   24320       // scores at 0: (2,19,128,5)
#define OUT_FEAT  38912       // agg: (2,19,128,3), feat: (2,19,128,128)

typedef short bf16x8 __attribute__((ext_vector_type(8)));   // 8 bf16 = 4 VGPR
typedef float f32x4  __attribute__((ext_vector_type(4)));
typedef int   v4i    __attribute__((ext_vector_type(4)));
typedef int   v2i    __attribute__((ext_vector_type(2)));

// exact IEEE fp32 squared distance, no FMA contraction, ((d0^2+d1^2)+d2^2)
__device__ __forceinline__ float dist2f(float a0, float a1, float a2,
                                        float b0, float b1, float b2) {
#pragma clang fp contract(off)
  float d0 = a0 - b0;
  float d1 = a1 - b1;
  float d2 = a2 - b2;
  return d0 * d0 + d1 * d1 + d2 * d2;
}

// exact 3-way bf16 truncation split: v == hi + mid + lo (to full fp32 precision)
__device__ __forceinline__ void split3(float v, unsigned& uh, unsigned& um, unsigned& ul) {
  unsigned u = __float_as_uint(v);
  uh = u & 0xffff0000u;
  float r1 = v - __uint_as_float(uh);
  unsigned u1 = __float_as_uint(r1);
  um = u1 & 0xffff0000u;
  float r2 = r1 - __uint_as_float(um);
  ul = __float_as_uint(r2);          // residual has <=8 mantissa bits -> top16 exact
}

// pack two fp32-high-halves into one dword of 2 bf16 (a -> low short, b -> high)
__device__ __forceinline__ unsigned pack_bf(unsigned ua, unsigned ub) {
  return (ub & 0xffff0000u) | (ua >> 16);
}

// ---------------- prep: fold BN, transpose weights ----------------
__global__ __launch_bounds__(256) void prep_kernel(
    const float* __restrict__ m1w, const float* __restrict__ m1g, const float* __restrict__ m1be,
    const float* __restrict__ m2w, const float* __restrict__ m2b, const float* __restrict__ m2g, const float* __restrict__ m2be,
    const float* __restrict__ m3w, const float* __restrict__ m3b, const float* __restrict__ m3g, const float* __restrict__ m3be,
    const float* __restrict__ c1w, const float* __restrict__ c1b, const float* __restrict__ c1g, const float* __restrict__ c1be,
    const float* __restrict__ c2w, const float* __restrict__ c2b, const float* __restrict__ c2g, const float* __restrict__ c2be,
    float* __restrict__ prep, float* __restrict__ wt)
{
  int t = threadIdx.x;
  float inv = 1.0f / sqrtf(1.0f + 1e-5f);
  if (t < 128) {
    float a1 = m1g[t] * inv;
    prep[t] = a1;                      // alpha1 (used by w1f_kernel prescale)
    prep[128 + t] = m1be[t];
    float a2 = m2g[t] * inv;  prep[256 + t] = a2;  prep[384 + t] = fmaf(m2b[t], a2, m2be[t]);
    float a3 = m3g[t] * inv;  prep[512 + t] = a3;  prep[640 + t] = fmaf(m3b[t], a3, m3be[t]);
    float ac1 = c1g[t] * inv; prep[768 + t] = ac1; prep[896 + t] = fmaf(c1b[t], ac1, c1be[t]);
    float ac2 = c2g[t] * inv; prep[1024 + t] = ac2; prep[1152 + t] = fmaf(c2b[t], ac2, c2be[t]);
    // packed per-channel consts for h1 build: {wx0*a1, wx1*a1, wx2*a1, be1}
    prep[1280 + 4 * t + 0] = m1w[t * 259 + 0] * a1;
    prep[1280 + 4 * t + 1] = m1w[t * 259 + 1] * a1;
    prep[1280 + 4 * t + 2] = m1w[t * 259 + 2] * a1;
    prep[1280 + 4 * t + 3] = m1be[t];
  }
  for (int i = t; i < 16384; i += 256) {
    int c = i >> 7, o = i & 127;
    wt[32768 + i]  = c1w[o * 128 + c];   // c1t[c][o]
    wt[49152 + i]  = c2w[o * 128 + c];   // c2t[c][o]
  }
  for (int i = t; i < 32768; i += 256) {
    int c = i >> 7, o = i & 127;
    wt[65536 + i] = m1w[o * 259 + 3 + c]; // w1t[c][o] (feature part)
  }
}

// ---------------- wsplit: pre-split w2/w3 into MFMA A-fragment layout ----------------
// Wf[l][sp][kk][ot] is a 512-short fragment block: lane*8 + j, where for
// A[m][k] of 16x16x32: m = ot*16 + (lane&15), k(c) = kk*32 + (lane>>4)*8 + j.
__global__ __launch_bounds__(256) void wsplit_kernel(
    const float* __restrict__ m2w, const float* __restrict__ m3w, short* __restrict__ Wf)
{
  int idx = blockIdx.x * 256 + threadIdx.x;      // 0..8191
#pragma unroll
  for (int e = 0; e < 4; ++e) {
    int i = idx * 4 + e;                         // 0..32767 = (l*128+o)*128 + c
    int c = i & 127, o = (i >> 7) & 127, l = i >> 14;
    float w = (l ? m3w : m2w)[o * 128 + c];
    unsigned uh, um, ul;
    split3(w, uh, um, ul);
    int ot = o >> 4, ml = o & 15, kk = c >> 5, q = (c & 31) >> 3, j = c & 7;
    int within = (q * 16 + ml) * 8 + j;
    Wf[(((l * 3 + 0) * 4 + kk) * 8 + ot) * 512 + within] = (short)(uh >> 16);
    Wf[(((l * 3 + 1) * 4 + kk) * 8 + ot) * 512 + within] = (short)(um >> 16);
    Wf[(((l * 3 + 2) * 4 + kk) * 8 + ot) * 512 + within] = (short)(ul >> 16);
  }
}

// ---------------- FPS: one wave per batch, bit-exact vs reference ----------------
__global__ __launch_bounds__(64) void fps_kernel(const float* __restrict__ xyz,
    float* __restrict__ xc, float* __restrict__ nxyz, float* __restrict__ agg)
{
  int bk = blockIdx.x, lane = threadIdx.x;
  int b = bk / 19, k = bk % 19;
  __shared__ float sx0[1024], sx1[1024], sx2[1024];
  for (int i = lane; i < 1024; i += 64) {
    const float* src = xyz + ((size_t)((b * 1024 + i) * 19 + k)) * 3;
    float v0 = src[0], v1 = src[1], v2 = src[2];
    sx0[i] = v0; sx1[i] = v1; sx2[i] = v2;
    xc[(bk * 3 + 0) * 1024 + i] = v0;
    xc[(bk * 3 + 1) * 1024 + i] = v1;
    xc[(bk * 3 + 2) * 1024 + i] = v2;
  }
  __syncthreads();
  float dist[16];
#pragma unroll
  for (int j = 0; j < 16; ++j) dist[j] = 1e10f;
  int far = 0;
  for (int t = 0; t < 128; ++t) {
    float c0 = sx0[far], c1 = sx1[far], c2 = sx2[far];
    if (lane < 3) {
      float cv = (lane == 0) ? c0 : ((lane == 1) ? c1 : c2);
      nxyz[(bk * 128 + t) * 3 + lane] = cv;
      agg[(bk * 128 + t) * 3 + lane]  = cv;
    }
    unsigned long long best = 0ull;
#pragma unroll
    for (int j = 0; j < 16; ++j) {
      int m = j * 64 + lane;
      float d = dist2f(sx0[m], sx1[m], sx2[m], c0, c1, c2);
      float dj = fminf(dist[j], d);
      dist[j] = dj;
      // max dist wins; ties -> smallest index (matches jnp.argmax first-max)
      unsigned long long key =
          ((unsigned long long)__float_as_uint(dj) << 32) | (unsigned)(1023 - m);
      if (key > best) best = key;
    }
#pragma unroll
    for (int off = 32; off > 0; off >>= 1) {
      unsigned hi = (unsigned)(best >> 32), lo = (unsigned)(best & 0xffffffffu);
      unsigned h2 = __shfl_xor(hi, off);
      unsigned l2 = __shfl_xor(lo, off);
      unsigned long long ob = ((unsigned long long)h2 << 32) | l2;
      if (ob > best) best = ob;
    }
    far = 1023 - (int)(best & 0xffffffffu);
  }
}

// ---------------- ball query: one wave per (bk,p) ----------------
__global__ __launch_bounds__(64) void ball_kernel(const float* __restrict__ xc,
    const float* __restrict__ nxyz, int* __restrict__ bidx)
{
  int gb = blockIdx.x;
  int bk = gb >> 7, p = gb & 127, lane = threadIdx.x;
  const float* x0 = xc + (bk * 3 + 0) * 1024;
  const float* x1 = xc + (bk * 3 + 1) * 1024;
  const float* x2 = xc + (bk * 3 + 2) * 1024;
  float c0 = nxyz[(bk * 128 + p) * 3 + 0];
  float c1 = nxyz[(bk * 128 + p) * 3 + 1];
  float c2 = nxyz[(bk * 128 + p) * 3 + 2];
  int* out = bidx + ((size_t)gb) * 128;
  int count = 0, first = 0;
  bool got = false;
  for (int ch = 0; ch < 16 && count < 128; ++ch) {
    int m = (ch << 6) + lane;
    float d = dist2f(x0[m], x1[m], x2[m], c0, c1, c2);
    bool flag = d < 0.0225f;                 // strict fp32 compare, RADIUS^2
    unsigned long long mask = __ballot(flag);
    if (!got && mask) { first = (ch << 6) + __builtin_ctzll(mask); got = true; }
    int pos = count + (int)__popcll(mask & ((1ull << lane) - 1ull));
    if (flag && pos < 128) out[pos] = m;
    count += (int)__popcll(mask);
  }
  for (int j = count + lane; j < 128; j += 64) out[j] = first;
}

// ---------------- W1f: per-point layer-1 feature GEMM (prescaled by alpha1) ----------------
__global__ __launch_bounds__(256) void w1f_kernel(const float* __restrict__ feats,
    const float* __restrict__ m1b, const float* __restrict__ prep,
    const float* __restrict__ wt, float* __restrict__ W1f)
{
  int blk = blockIdx.x;
  int bk = blk >> 5;
  int m0 = (blk & 31) << 5;
  int b = bk / 19, k = bk % 19;
  int t = threadIdx.x;
  int o = t & 127, mg = t >> 7;
  __shared__ __align__(16) float sf[8][32];
  const float* w1t = wt + 65536;
  float acc[16];
#pragma unroll
  for (int j = 0; j < 16; ++j) acc[j] = 0.f;
  for (int cc = 0; cc < 256; cc += 8) {
    __syncthreads();
    {
      int c = t >> 5, mm = t & 31;
      sf[c][mm] = feats[((size_t)((b * 256 + cc + c) * 19 + k)) * 1024 + m0 + mm];
    }
    __syncthreads();
#pragma unroll
    for (int c = 0; c < 8; ++c) {
      float wv = w1t[(cc + c) * 128 + o];
      const float4* sp = (const float4*)&sf[c][mg * 16];
      float4 f0 = sp[0], f1 = sp[1], f2 = sp[2], f3 = sp[3];
      acc[0]  = fmaf(wv, f0.x, acc[0]);  acc[1]  = fmaf(wv, f0.y, acc[1]);
      acc[2]  = fmaf(wv, f0.z, acc[2]);  acc[3]  = fmaf(wv, f0.w, acc[3]);
      acc[4]  = fmaf(wv, f1.x, acc[4]);  acc[5]  = fmaf(wv, f1.y, acc[5]);
      acc[6]  = fmaf(wv, f1.z, acc[6]);  acc[7]  = fmaf(wv, f1.w, acc[7]);
      acc[8]  = fmaf(wv, f2.x, acc[8]);  acc[9]  = fmaf(wv, f2.y, acc[9]);
      acc[10] = fmaf(wv, f2.z, acc[10]); acc[11] = fmaf(wv, f2.w, acc[11]);
      acc[12] = fmaf(wv, f3.x, acc[12]); acc[13] = fmaf(wv, f3.y, acc[13]);
      acc[14] = fmaf(wv, f3.z, acc[14]); acc[15] = fmaf(wv, f3.w, acc[15]);
    }
  }
  float bb = m1b[o], al = prep[o];
#pragma unroll
  for (int j = 0; j < 16; ++j) {
    int m = m0 + mg * 16 + j;
    W1f[((size_t)(bk * 1024 + m)) * 128 + o] = (acc[j] + bb) * al;
  }
}

// ---------------- MFMA GEMM over one 128(c) x 64(s) fragment buffer ----------------
// hfrag layout: [sp 3][kk 4][st 4] blocks of 512 shorts (lane*8 + j).
// Wave owns o-tiles {2w, 2w+1}; acc[oi][st] is the 16x16 C tile.
__device__ __forceinline__ void mfma_layer(const short* __restrict__ Wf,
                                           const short* hfrag, int l,
                                           int wave, int lane, f32x4 acc[2][4])
{
#pragma unroll 1
  for (int kk = 0; kk < 4; ++kk) {
    bf16x8 a[2][3];
#pragma unroll
    for (int oi = 0; oi < 2; ++oi)
#pragma unroll
      for (int sp = 0; sp < 3; ++sp)
        a[oi][sp] = *(const bf16x8*)(Wf + (((l * 3 + sp) * 4 + kk) * 8 + (wave * 2 + oi)) * 512 + lane * 8);
#pragma unroll
    for (int st = 0; st < 4; ++st) {
      const short* hb = hfrag + kk * 2048 + st * 512 + lane * 8;
      bf16x8 b0 = *(const bf16x8*)(hb);           // hi
      bf16x8 b1 = *(const bf16x8*)(hb + 8192);    // mid
      bf16x8 b2 = *(const bf16x8*)(hb + 16384);   // lo
#pragma unroll
      for (int oi = 0; oi < 2; ++oi) {
        f32x4 c = acc[oi][st];
        // smallest terms first: lo*hi, mid*mid, hi*lo, mid*hi, hi*mid, hi*hi
        c = __builtin_amdgcn_mfma_f32_16x16x32_bf16(a[oi][2], b0, c, 0, 0, 0);
        c = __builtin_amdgcn_mfma_f32_16x16x32_bf16(a[oi][1], b1, c, 0, 0, 0);
        c = __builtin_amdgcn_mfma_f32_16x16x32_bf16(a[oi][0], b2, c, 0, 0, 0);
        c = __builtin_amdgcn_mfma_f32_16x16x32_bf16(a[oi][1], b0, c, 0, 0, 0);
        c = __builtin_amdgcn_mfma_f32_16x16x32_bf16(a[oi][0], b1, c, 0, 0, 0);
        c = __builtin_amdgcn_mfma_f32_16x16x32_bf16(a[oi][0], b0, c, 0, 0, 0);
        acc[oi][st] = c;
      }
    }
  }
}

// ---------------- fused SA: h1 build -> layer2 -> layer3 -> max, via MFMA ----------------
__global__ __launch_bounds__(256, 3) void sa_kernel(
    const float* __restrict__ xc, const float* __restrict__ nxyz,
    const int* __restrict__ bidx, const float* __restrict__ W1f,
    const float* __restrict__ prep, const short* __restrict__ Wf,
    float* __restrict__ feat_out)
{
  __shared__ __align__(16) short hfrag[24576];   // 48KB: 3 splits x 128c x 64s bf16 frags
  __shared__ float pcs[512];                     // layer-1 xyz consts {w0,w1,w2,be}*128
  int gb = blockIdx.x, bk = gb >> 7, p = gb & 127;
  int t = threadIdx.x;
  int wave = t >> 6, lane = t & 63;
  int quad = lane >> 4, nl = lane & 15;

  pcs[t] = prep[1280 + t];
  pcs[256 + t] = prep[1536 + t];

  float cen0 = nxyz[(bk * 128 + p) * 3 + 0];
  float cen1 = nxyz[(bk * 128 + p) * 3 + 1];
  float cen2 = nxyz[(bk * 128 + p) * 3 + 2];

  float rmax[2][4] = {{0.f, 0.f, 0.f, 0.f}, {0.f, 0.f, 0.f, 0.f}};
  __syncthreads();

  for (int hh = 0; hh < 2; ++hh) {
    // ---- h1 build: wave w = c-block w (kk=w), lane = s within half ----
    {
      int s_l = lane;                  // 0..63
      int cg = wave;                   // kk for this thread's 32 channels
      int st = s_l >> 4, sl = s_l & 15;
      int m = bidx[((size_t)gb) * 128 + hh * 64 + s_l];
      float g0 = (xc[(bk * 3 + 0) * 1024 + m] - cen0) * (1.0f / 0.15f);
      float g1 = (xc[(bk * 3 + 1) * 1024 + m] - cen1) * (1.0f / 0.15f);
      float g2 = (xc[(bk * 3 + 2) * 1024 + m] - cen2) * (1.0f / 0.15f);
      const float4* wrow = (const float4*)(W1f + ((size_t)(bk * 1024 + m)) * 128 + cg * 32);
      const float4* pcp = (const float4*)pcs + cg * 32;
#pragma unroll
      for (int g = 0; g < 4; ++g) {
        float4 wva = wrow[g * 2], wvb = wrow[g * 2 + 1];
        float hv[8];
        float wv[8] = {wva.x, wva.y, wva.z, wva.w, wvb.x, wvb.y, wvb.z, wvb.w};
#pragma unroll
        for (int e = 0; e < 8; ++e) {
          float4 pc = pcp[g * 8 + e];
          hv[e] = fmaxf(wv[e] + pc.x * g0 + pc.y * g1 + pc.z * g2 + pc.w, 0.f);
        }
        unsigned uh[8], um[8], ul[8];
#pragma unroll
        for (int e = 0; e < 8; ++e) split3(hv[e], uh[e], um[e], ul[e]);
        int base = (cg * 4 + st) * 512 + (g * 16 + sl) * 8;   // sp0
        v4i ph = {(int)pack_bf(uh[0], uh[1]), (int)pack_bf(uh[2], uh[3]),
                  (int)pack_bf(uh[4], uh[5]), (int)pack_bf(uh[6], uh[7])};
        *(v4i*)&hfrag[base] = ph;
        v4i pm = {(int)pack_bf(um[0], um[1]), (int)pack_bf(um[2], um[3]),
                  (int)pack_bf(um[4], um[5]), (int)pack_bf(um[6], um[7])};
        *(v4i*)&hfrag[base + 8192] = pm;
        v4i pl = {(int)pack_bf(ul[0], ul[1]), (int)pack_bf(ul[2], ul[3]),
                  (int)pack_bf(ul[4], ul[5]), (int)pack_bf(ul[6], ul[7])};
        *(v4i*)&hfrag[base + 16384] = pl;
      }
    }
    __syncthreads();

    // ---- layer 2 (l=0) ----
    f32x4 acc[2][4];
#pragma unroll
    for (int oi = 0; oi < 2; ++oi)
#pragma unroll
      for (int st = 0; st < 4; ++st) acc[oi][st] = (f32x4){0.f, 0.f, 0.f, 0.f};
    mfma_layer(Wf, hfrag, 0, wave, lane, acc);
    __syncthreads();                              // all hfrag reads done

    // ---- h2 epilogue: BN+ReLU, split, write back as fragments ----
#pragma unroll
    for (int oi = 0; oi < 2; ++oi) {
      int o0 = (wave * 2 + oi) * 16 + quad * 4;
      float4 al = *(const float4*)&prep[256 + o0];
      float4 be = *(const float4*)&prep[384 + o0];
      int kk2 = o0 >> 5, g2 = (o0 & 31) >> 3, j0 = o0 & 7;    // j0 in {0,4}
#pragma unroll
      for (int st = 0; st < 4; ++st) {
        f32x4 cc = acc[oi][st];
        float v0 = fmaxf(fmaf(cc[0], al.x, be.x), 0.f);
        float v1 = fmaxf(fmaf(cc[1], al.y, be.y), 0.f);
        float v2 = fmaxf(fmaf(cc[2], al.z, be.z), 0.f);
        float v3 = fmaxf(fmaf(cc[3], al.w, be.w), 0.f);
        unsigned h0, m0, l0, h1, m1, l1, h2, m2, l2, h3, m3, l3;
        split3(v0, h0, m0, l0); split3(v1, h1, m1, l1);
        split3(v2, h2, m2, l2); split3(v3, h3, m3, l3);
        int base = (kk2 * 4 + st) * 512 + (g2 * 16 + nl) * 8 + j0;
        v2i w0 = {(int)pack_bf(h0, h1), (int)pack_bf(h2, h3)};
        *(v2i*)&hfrag[base] = w0;
        v2i w1 = {(int)pack_bf(m0, m1), (int)pack_bf(m2, m3)};
        *(v2i*)&hfrag[base + 8192] = w1;
        v2i w2 = {(int)pack_bf(l0, l1), (int)pack_bf(l2, l3)};
        *(v2i*)&hfrag[base + 16384] = w2;
      }
    }
    __syncthreads();

    // ---- layer 3 (l=1) ----
#pragma unroll
    for (int oi = 0; oi < 2; ++oi)
#pragma unroll
      for (int st = 0; st < 4; ++st) acc[oi][st] = (f32x4){0.f, 0.f, 0.f, 0.f};
    mfma_layer(Wf, hfrag, 1, wave, lane, acc);

    // ---- layer-3 epilogue: BN+ReLU+max over this half's samples ----
#pragma unroll
    for (int oi = 0; oi < 2; ++oi) {
      int o0 = (wave * 2 + oi) * 16 + quad * 4;
      float4 al = *(const float4*)&prep[512 + o0];
      float4 be = *(const float4*)&prep[640 + o0];
#pragma unroll
      for (int st = 0; st < 4; ++st) {
        f32x4 cc = acc[oi][st];
        rmax[oi][0] = fmaxf(rmax[oi][0], fmaxf(fmaf(cc[0], al.x, be.x), 0.f));
        rmax[oi][1] = fmaxf(rmax[oi][1], fmaxf(fmaf(cc[1], al.y, be.y), 0.f));
        rmax[oi][2] = fmaxf(rmax[oi][2], fmaxf(fmaf(cc[2], al.z, be.z), 0.f));
        rmax[oi][3] = fmaxf(rmax[oi][3], fmaxf(fmaf(cc[3], al.w, be.w), 0.f));
      }
    }
    __syncthreads();                              // hfrag reads done before next half
  }

  // ---- reduce max across the 16 s-lanes, write feat ----
#pragma unroll
  for (int oi = 0; oi < 2; ++oi)
#pragma unroll
    for (int r = 0; r < 4; ++r) {
      float v = rmax[oi][r];
      v = fmaxf(v, __shfl_xor(v, 1));
      v = fmaxf(v, __shfl_xor(v, 2));
      v = fmaxf(v, __shfl_xor(v, 4));
      v = fmaxf(v, __shfl_xor(v, 8));
      if (nl == 0) {
        int o = (wave * 2 + oi) * 16 + quad * 4 + r;
        feat_out[(((size_t)bk) << 14) + (o << 7) + p] = v;
      }
    }
}

// 8x8 register-tile GEMM over a 128x128 LDS operand; w is [c][o] in global
__device__ __forceinline__ void gemm_tile(const float* __restrict__ w,
                                          const float* lds, int tx, int ty,
                                          float acc[8][8])
{
#pragma unroll
  for (int i = 0; i < 8; ++i)
#pragma unroll
    for (int j = 0; j < 8; ++j) acc[i][j] = 0.f;
  for (int c = 0; c < 128; ++c) {
    const float4* wr = (const float4*)(w + c * 128 + ty * 8);
    float4 a0 = wr[0], a1 = wr[1];
    const float4* hr = (const float4*)(lds + c * 128 + tx * 8);
    float4 b0 = hr[0], b1 = hr[1];
    float av[8] = {a0.x, a0.y, a0.z, a0.w, a1.x, a1.y, a1.z, a1.w};
    float bv[8] = {b0.x, b0.y, b0.z, b0.w, b1.x, b1.y, b1.z, b1.w};
#pragma unroll
    for (int i = 0; i < 8; ++i)
#pragma unroll
      for (int j = 0; j < 8; ++j) acc[i][j] = fmaf(av[i], bv[j], acc[i][j]);
  }
}

// ---------------- head: c1 -> c2 -> op -> scores ----------------
__global__ __launch_bounds__(256) void head_kernel(const float* __restrict__ featg,
    const float* __restrict__ prep, const float* __restrict__ wt,
    const float* __restrict__ nxyz, const float* __restrict__ opw,
    const float* __restrict__ opb, float* __restrict__ scores)
{
  __shared__ __align__(16) float buf[128 * 128];
  int bk = blockIdx.x, t = threadIdx.x;
  for (int i = t; i < 16384; i += 256) buf[i] = featg[(bk << 14) + i];
  __syncthreads();
  int tx = t & 15, ty = t >> 4;
  float acc[8][8];

  // c1
  gemm_tile(wt + 32768, buf, tx, ty, acc);
  __syncthreads();
#pragma unroll
  for (int i = 0; i < 8; ++i) {
    int o = ty * 8 + i;
    float al = prep[768 + o], be = prep[896 + o];
#pragma unroll
    for (int j = 0; j < 8; ++j)
      buf[o * 128 + tx * 8 + j] = fmaxf(fmaf(acc[i][j], al, be), 0.f);
  }
  __syncthreads();

  // c2
  gemm_tile(wt + 49152, buf, tx, ty, acc);
  __syncthreads();
#pragma unroll
  for (int i = 0; i < 8; ++i) {
    int o = ty * 8 + i;
    float al = prep[1024 + o], be = prep[1152 + o];
#pragma unroll
    for (int j = 0; j < 8; ++j)
      buf[o * 128 + tx * 8 + j] = fmaxf(fmaf(acc[i][j], al, be), 0.f);
  }
  __syncthreads();

  // op head + scores assembly
  if (t < 128) {
    int p = t, k = bk % 19;
    float res[5];
#pragma unroll
    for (int j = 0; j < 5; ++j) {
      const float* wr = opw + ((size_t)(k * 5 + j)) * 128;
      float a = opb[k * 5 + j];
      for (int c = 0; c < 128; ++c) a = fmaf(wr[c], buf[c * 128 + p], a);
      res[j] = a;
    }
    float a0 = nxyz[(bk * 128 + p) * 3 + 0];
    float a1 = nxyz[(bk * 128 + p) * 3 + 1];
    float a2 = nxyz[(bk * 128 + p) * 3 + 2];
    float* sc = scores + ((size_t)(bk * 128 + p)) * 5;
    sc[0] = res[0];
    sc[1] = res[1];
    sc[2] = a0 + res[2];
    sc[3] = a1 + res[3];
    sc[4] = a2 + res[4];
  }
}

extern "C" void kernel_launch(void* const* d_in, const int* in_sizes, int n_in,
                              void* d_out, int out_size, void* d_ws, size_t ws_size,
                              hipStream_t stream) {
  (void)in_sizes; (void)n_in; (void)out_size; (void)ws_size;
  const float* xyz  = (const float*)d_in[0];
  const float* fts  = (const float*)d_in[1];
  const float* m1w  = (const float*)d_in[2];
  const float* m1b  = (const float*)d_in[3];
  const float* m1g  = (const float*)d_in[4];
  const float* m1be = (const float*)d_in[5];
  const float* m2w  = (const float*)d_in[6];
  const float* m2b  = (const float*)d_in[7];
  const float* m2g  = (const float*)d_in[8];
  const float* m2be = (const float*)d_in[9];
  const float* m3w  = (const float*)d_in[10];
  const float* m3b  = (const float*)d_in[11];
  const float* m3g  = (const float*)d_in[12];
  const float* m3be = (const float*)d_in[13];
  const float* c1w  = (const float*)d_in[14];
  const float* c1b  = (const float*)d_in[15];
  const float* c1g  = (const float*)d_in[16];
  const float* c1be = (const float*)d_in[17];
  const float* c2w  = (const float*)d_in[18];
  const float* c2b  = (const float*)d_in[19];
  const float* c2g  = (const float*)d_in[20];
  const float* c2be = (const float*)d_in[21];
  const float* opw  = (const float*)d_in[22];
  const float* opb  = (const float*)d_in[23];

  float* out = (float*)d_out;
  char* ws = (char*)d_ws;
  float* xc   = (float*)(ws + OFF_XC);
  float* nxyz = (float*)(ws + OFF_NXYZ);
  int*   bidx = (int*)(ws + OFF_BIDX);
  float* W1f  = (float*)(ws + OFF_W1F);
  float* prep = (float*)(ws + OFF_PREP);
  float* wt   = (float*)(ws + OFF_WT);
  short* Wf   = (short*)(ws + OFF_WF);

  hipLaunchKernelGGL(prep_kernel, dim3(1), dim3(256), 0, stream,
                     m1w, m1g, m1be, m2w, m2b, m2g, m2be, m3w, m3b, m3g, m3be,
                     c1w, c1b, c1g, c1be, c2w, c2b, c2g, c2be, prep, wt);
  hipLaunchKernelGGL(wsplit_kernel, dim3(32), dim3(256), 0, stream, m2w, m3w, Wf);
  hipLaunchKernelGGL(fps_kernel, dim3(NBK), dim3(64), 0, stream,
                     xyz, xc, nxyz, out + OUT_AGG);
  hipLaunchKernelGGL(ball_kernel, dim3(NBK * 128), dim3(64), 0, stream,
                     xc, nxyz, bidx);
  hipLaunchKernelGGL(w1f_kernel, dim3(NBK * 32), dim3(256), 0, stream,
                     fts, m1b, prep, wt, W1f);
  hipLaunchKernelGGL(sa_kernel, dim3(NBK * 128), dim3(256), 0, stream,
                     xc, nxyz, bidx, W1f, prep, Wf, out + OUT_FEAT);
  hipLaunchKernelGGL(head_kernel, dim3(NBK), dim3(256), 0, stream,
                     out + OUT_FEAT, prep, wt, nxyz, opw, opb, out);
}

// Round 3
// 482.421 us; speedup vs baseline: 1.8223x; 1.1474x over previous
//
#include <hip/hip_runtime.h>
#include <math.h>

// ---------------- problem constants ----------------
// B=2, K=19 -> BK=38 batches; M=1024 points; C=256 feat ch; NPOINT=NSAMPLE=128
#define NBK   38

// ---------------- workspace layout (bytes) ----------------
#define OFF_XC    0u          // [38][3][1024] f32        = 466944
#define OFF_NXYZ  466944u     // [38][128][3]  f32        = 58368
#define OFF_BIDX  525312u     // [38][128][128] i32       = 2490368
#define OFF_W1F   3015680u    // [38][1024][128] f32      = 19922944
#define OFF_PREP  22938624u   // 4096 f32
#define OFF_WT    22955008u   // 32768 f32: c1t (0), c2t (16384)
#define OFF_WF    23086080u   // 131072 shorts: w2/w3 A-frags (0..65535), w1feat A-frags (65536..)

// ---------------- d_out layout (float offsets) ----------------
#define OUT_AGG   24320       // scores at 0: (2,19,128,5)
#define OUT_FEAT  38912       // agg: (2,19,128,3), feat: (2,19,128,128)

typedef short bf16x8 __attribute__((ext_vector_type(8)));   // 8 bf16 = 4 VGPR
typedef float f32x4  __attribute__((ext_vector_type(4)));
typedef int   v4i    __attribute__((ext_vector_type(4)));
typedef int   v2i    __attribute__((ext_vector_type(2)));

// exact IEEE fp32 squared distance, no FMA contraction, ((d0^2+d1^2)+d2^2)
__device__ __forceinline__ float dist2f(float a0, float a1, float a2,
                                        float b0, float b1, float b2) {
#pragma clang fp contract(off)
  float d0 = a0 - b0;
  float d1 = a1 - b1;
  float d2 = a2 - b2;
  return d0 * d0 + d1 * d1 + d2 * d2;
}

// 2-way bf16 split with round-to-nearest-even: v ~= hi + mid, residual <= 2^-18 |v|
// returns the two bf16 bit patterns in the LOW 16 bits of sh/sm.
__device__ __forceinline__ void split2rn(float v, unsigned& sh, unsigned& sm) {
  unsigned u = __float_as_uint(v);
  unsigned rh = (u + 0x7fffu + ((u >> 16) & 1u)) & 0xffff0000u;
  sh = rh >> 16;
  float r1 = v - __uint_as_float(rh);        // exact in fp32
  unsigned u1 = __float_as_uint(r1);
  unsigned rm = (u1 + 0x7fffu + ((u1 >> 16) & 1u)) & 0xffff0000u;
  sm = rm >> 16;
}

// ---------------- prep: fold BN constants ----------------
__global__ __launch_bounds__(256) void prep_kernel(
    const float* __restrict__ m1w, const float* __restrict__ m1g, const float* __restrict__ m1be,
    const float* __restrict__ m2b, const float* __restrict__ m2g, const float* __restrict__ m2be,
    const float* __restrict__ m3b, const float* __restrict__ m3g, const float* __restrict__ m3be,
    const float* __restrict__ c1b, const float* __restrict__ c1g, const float* __restrict__ c1be,
    const float* __restrict__ c2b, const float* __restrict__ c2g, const float* __restrict__ c2be,
    float* __restrict__ prep)
{
  int t = threadIdx.x;
  if (t < 128) {
    float inv = 1.0f / sqrtf(1.0f + 1e-5f);
    float a1 = m1g[t] * inv;
    prep[t] = a1;                      // alpha1 (used by w1f epilogue)
    float a2 = m2g[t] * inv;  prep[256 + t] = a2;  prep[384 + t] = fmaf(m2b[t], a2, m2be[t]);
    float a3 = m3g[t] * inv;  prep[512 + t] = a3;  prep[640 + t] = fmaf(m3b[t], a3, m3be[t]);
    float ac1 = c1g[t] * inv; prep[768 + t] = ac1; prep[896 + t] = fmaf(c1b[t], ac1, c1be[t]);
    float ac2 = c2g[t] * inv; prep[1024 + t] = ac2; prep[1152 + t] = fmaf(c2b[t], ac2, c2be[t]);
    // packed per-channel consts for h1 build: {wx0*a1, wx1*a1, wx2*a1, be1}
    prep[1280 + 4 * t + 0] = m1w[t * 259 + 0] * a1;
    prep[1280 + 4 * t + 1] = m1w[t * 259 + 1] * a1;
    prep[1280 + 4 * t + 2] = m1w[t * 259 + 2] * a1;
    prep[1280 + 4 * t + 3] = m1be[t];
  }
}

// ---------------- wsplit: pre-split weights into MFMA A-fragment layout ----------
// A-frag block of 512 shorts, index (q*16 + m-in-tile)*8 + j; read as lane*8+j.
// w2/w3: Wf[((l*2+sp)*4+kk)*8+ot]. w1feat: Wf+65536, [(sp*8+kk)*8+ot].
// Also emits c1t/c2t transposes for head_kernel.
__global__ __launch_bounds__(256) void wsplit_kernel(
    const float* __restrict__ m1w, const float* __restrict__ m2w,
    const float* __restrict__ m3w, const float* __restrict__ c1w,
    const float* __restrict__ c2w, short* __restrict__ Wf, float* __restrict__ wt)
{
  int idx = blockIdx.x * 256 + threadIdx.x;      // 0..16383 (64 blocks)
#pragma unroll
  for (int e = 0; e < 4; ++e) {
    int i = idx * 4 + e;                         // 0..65535
    if (i < 32768) {
      int c = i & 127, o = (i >> 7) & 127, l = i >> 14;
      float w = (l ? m3w : m2w)[o * 128 + c];
      unsigned sh, sm;
      split2rn(w, sh, sm);
      int ot = o >> 4, mm = o & 15, kk = c >> 5, q = (c & 31) >> 3, j = c & 7;
      int within = (q * 16 + mm) * 8 + j;
      Wf[(((l * 2 + 0) * 4 + kk) * 8 + ot) * 512 + within] = (short)sh;
      Wf[(((l * 2 + 1) * 4 + kk) * 8 + ot) * 512 + within] = (short)sm;
    } else {
      int jdx = i - 32768;
      int o = jdx >> 8, c = jdx & 255;
      float w = m1w[o * 259 + 3 + c];
      unsigned sh, sm;
      split2rn(w, sh, sm);
      int ot = o >> 4, mm = o & 15, kk = c >> 5, q = (c & 31) >> 3, j = c & 7;
      int within = (q * 16 + mm) * 8 + j;
      Wf[65536 + ((kk) * 8 + ot) * 512 + within] = (short)sh;
      Wf[65536 + ((8 + kk) * 8 + ot) * 512 + within] = (short)sm;
    }
  }
  {
    int i = idx;                                  // 0..16383, exactly one pass
    int c = i >> 7, o = i & 127;
    wt[i] = c1w[o * 128 + c];                     // c1t[c][o]
    wt[16384 + i] = c2w[o * 128 + c];             // c2t[c][o]
  }
}

// ---------------- FPS: one 1024-thread block per batch, bit-exact ----------------
__global__ __launch_bounds__(1024) void fps_kernel(const float* __restrict__ xyz,
    float* __restrict__ xc, float* __restrict__ nxyz, float* __restrict__ agg)
{
  int bk = blockIdx.x, t = threadIdx.x;
  int b = bk / 19, k = bk % 19;
  int wave = t >> 6, lane = t & 63;
  __shared__ float sx0[1024], sx1[1024], sx2[1024];
  __shared__ unsigned long long skey[16];
  __shared__ int sfar;
  const float* src = xyz + ((size_t)((b * 1024 + t) * 19 + k)) * 3;
  float x0 = src[0], x1 = src[1], x2 = src[2];
  sx0[t] = x0; sx1[t] = x1; sx2[t] = x2;
  xc[(bk * 3 + 0) * 1024 + t] = x0;
  xc[(bk * 3 + 1) * 1024 + t] = x1;
  xc[(bk * 3 + 2) * 1024 + t] = x2;
  if (t == 0) sfar = 0;
  float dist = 1e10f;
  __syncthreads();
  for (int it = 0; it < 128; ++it) {
    int far = sfar;
    float c0 = sx0[far], c1 = sx1[far], c2 = sx2[far];
    if (t < 3) {
      float cv = (t == 0) ? c0 : ((t == 1) ? c1 : c2);
      nxyz[(bk * 128 + it) * 3 + t] = cv;
      agg[(bk * 128 + it) * 3 + t]  = cv;
    }
    float d = dist2f(x0, x1, x2, c0, c1, c2);
    dist = fminf(dist, d);
    // max dist wins; ties -> smallest index (matches jnp.argmax first-max)
    unsigned long long best =
        ((unsigned long long)__float_as_uint(dist) << 32) | (unsigned)(1023 - t);
#pragma unroll
    for (int off = 32; off > 0; off >>= 1) {
      unsigned hi = (unsigned)(best >> 32), lo = (unsigned)best;
      unsigned h2 = __shfl_xor(hi, off);
      unsigned l2 = __shfl_xor(lo, off);
      unsigned long long ob = ((unsigned long long)h2 << 32) | l2;
      if (ob > best) best = ob;
    }
    if (lane == 0) skey[wave] = best;
    __syncthreads();
    if (t < 16) {
      unsigned long long bb = skey[t];
#pragma unroll
      for (int off = 8; off > 0; off >>= 1) {
        unsigned hi = (unsigned)(bb >> 32), lo = (unsigned)bb;
        unsigned h2 = __shfl_xor(hi, off);
        unsigned l2 = __shfl_xor(lo, off);
        unsigned long long ob = ((unsigned long long)h2 << 32) | l2;
        if (ob > bb) bb = ob;
      }
      if (t == 0) sfar = 1023 - (int)(bb & 0xffffffffu);
    }
    __syncthreads();
  }
}

// ---------------- ball query: one wave per (bk,p) ----------------
__global__ __launch_bounds__(64) void ball_kernel(const float* __restrict__ xc,
    const float* __restrict__ nxyz, int* __restrict__ bidx)
{
  int gb = blockIdx.x;
  int bk = gb >> 7, p = gb & 127, lane = threadIdx.x;
  const float* x0 = xc + (bk * 3 + 0) * 1024;
  const float* x1 = xc + (bk * 3 + 1) * 1024;
  const float* x2 = xc + (bk * 3 + 2) * 1024;
  float c0 = nxyz[(bk * 128 + p) * 3 + 0];
  float c1 = nxyz[(bk * 128 + p) * 3 + 1];
  float c2 = nxyz[(bk * 128 + p) * 3 + 2];
  int* out = bidx + ((size_t)gb) * 128;
  int count = 0, first = 0;
  bool got = false;
  for (int ch = 0; ch < 16 && count < 128; ++ch) {
    int m = (ch << 6) + lane;
    float d = dist2f(x0[m], x1[m], x2[m], c0, c1, c2);
    bool flag = d < 0.0225f;                 // strict fp32 compare, RADIUS^2
    unsigned long long mask = __ballot(flag);
    if (!got && mask) { first = (ch << 6) + __builtin_ctzll(mask); got = true; }
    int pos = count + (int)__popcll(mask & ((1ull << lane) - 1ull));
    if (flag && pos < 128) out[pos] = m;
    count += (int)__popcll(mask);
  }
  for (int j = count + lane; j < 128; j += 64) out[j] = first;
}

// ---------------- W1f: per-bk layer-1 feature GEMM via split2 MFMA ----------------
// W1f[bk][m][o] = (sum_c w1[o][3+c] * f[bk][c][m] + b1[o]) * alpha1[o]
__global__ __launch_bounds__(256, 2) void w1f_kernel(
    const float* __restrict__ feats, const float* __restrict__ m1b,
    const float* __restrict__ prep, const short* __restrict__ Wf,
    float* __restrict__ W1f)
{
  __shared__ __align__(16) short ffrag[16384];    // 32KB: [sp2][kkl2][st8]*512
  int blk = blockIdx.x;
  int bk = blk >> 3, m0 = (blk & 7) << 7;
  int b = bk / 19, k = bk % 19;
  int t = threadIdx.x;
  int wave = t >> 6, lane = t & 63;
  int quad = lane >> 4, nl = lane & 15;
  int mloc = t & 127, chalf = t >> 7;
  int st_w = mloc >> 4, sl_w = mloc & 15;
  const float* fbase = feats + ((size_t)(b * 4864 + k)) * 1024 + m0 + mloc;
  const short* WA = Wf + 65536;

  f32x4 acc[2][8];
#pragma unroll
  for (int oi = 0; oi < 2; ++oi)
#pragma unroll
    for (int st = 0; st < 8; ++st) acc[oi][st] = (f32x4){0.f, 0.f, 0.f, 0.f};

  for (int ch = 0; ch < 4; ++ch) {
    int cbase = ch * 64 + chalf * 32;
    // ---- stage 64 channels x 128 m as split2 B-frags ----
#pragma unroll
    for (int g = 0; g < 4; ++g) {
      float v[8];
#pragma unroll
      for (int j = 0; j < 8; ++j)
        v[j] = fbase[(size_t)(cbase + g * 8 + j) * 19456];
      unsigned sh[8], sm[8];
#pragma unroll
      for (int j = 0; j < 8; ++j) split2rn(v[j], sh[j], sm[j]);
      int base = chalf * 4096 + st_w * 512 + (g * 16 + sl_w) * 8;
      v4i ph = {(int)(sh[0] | (sh[1] << 16)), (int)(sh[2] | (sh[3] << 16)),
                (int)(sh[4] | (sh[5] << 16)), (int)(sh[6] | (sh[7] << 16))};
      *(v4i*)&ffrag[base] = ph;
      v4i pm = {(int)(sm[0] | (sm[1] << 16)), (int)(sm[2] | (sm[3] << 16)),
                (int)(sm[4] | (sm[5] << 16)), (int)(sm[6] | (sm[7] << 16))};
      *(v4i*)&ffrag[base + 8192] = pm;
    }
    __syncthreads();
    // ---- MFMA over the 2 kk groups of this chunk ----
#pragma unroll
    for (int kkl = 0; kkl < 2; ++kkl) {
      int kk = ch * 2 + kkl;
      bf16x8 a[2][2];
#pragma unroll
      for (int oi = 0; oi < 2; ++oi)
#pragma unroll
        for (int sp = 0; sp < 2; ++sp)
          a[oi][sp] = *(const bf16x8*)(WA + ((sp * 8 + kk) * 8 + wave * 2 + oi) * 512 + lane * 8);
#pragma unroll
      for (int st = 0; st < 8; ++st) {
        const short* hb = ffrag + kkl * 4096 + st * 512 + lane * 8;
        bf16x8 b0 = *(const bf16x8*)hb;
        bf16x8 b1 = *(const bf16x8*)(hb + 8192);
#pragma unroll
        for (int oi = 0; oi < 2; ++oi) {
          f32x4 c = acc[oi][st];
          c = __builtin_amdgcn_mfma_f32_16x16x32_bf16(a[oi][1], b0, c, 0, 0, 0);
          c = __builtin_amdgcn_mfma_f32_16x16x32_bf16(a[oi][0], b1, c, 0, 0, 0);
          c = __builtin_amdgcn_mfma_f32_16x16x32_bf16(a[oi][0], b0, c, 0, 0, 0);
          acc[oi][st] = c;
        }
      }
    }
    __syncthreads();
  }
  // ---- epilogue: (acc + b) * alpha, store ----
#pragma unroll
  for (int oi = 0; oi < 2; ++oi) {
    int o0 = (wave * 2 + oi) * 16 + quad * 4;
    float4 bb = *(const float4*)&m1b[o0];
    float4 al = *(const float4*)&prep[o0];
#pragma unroll
    for (int st = 0; st < 8; ++st) {
      int m_out = m0 + st * 16 + nl;
      f32x4 cc = acc[oi][st];
      float4 r;
      r.x = (cc[0] + bb.x) * al.x;
      r.y = (cc[1] + bb.y) * al.y;
      r.z = (cc[2] + bb.z) * al.z;
      r.w = (cc[3] + bb.w) * al.w;
      *(float4*)&W1f[((size_t)(bk * 1024 + m_out)) * 128 + o0] = r;
    }
  }
}

// ---------------- MFMA GEMM over one 128(c) x 64(s) fragment buffer ----------------
// hfrag: [sp 2][kk 4][st 4] blocks of 512 shorts (lane*8 + j), sp stride 8192.
__device__ __forceinline__ void mfma_layer(const short* __restrict__ Wf,
                                           const short* hfrag, int l,
                                           int wave, int lane, f32x4 acc[2][4])
{
#pragma unroll 1
  for (int kk = 0; kk < 4; ++kk) {
    bf16x8 a[2][2];
#pragma unroll
    for (int oi = 0; oi < 2; ++oi)
#pragma unroll
      for (int sp = 0; sp < 2; ++sp)
        a[oi][sp] = *(const bf16x8*)(Wf + (((l * 2 + sp) * 4 + kk) * 8 + (wave * 2 + oi)) * 512 + lane * 8);
#pragma unroll
    for (int st = 0; st < 4; ++st) {
      const short* hb = hfrag + kk * 2048 + st * 512 + lane * 8;
      bf16x8 b0 = *(const bf16x8*)(hb);           // hi
      bf16x8 b1 = *(const bf16x8*)(hb + 8192);    // mid
#pragma unroll
      for (int oi = 0; oi < 2; ++oi) {
        f32x4 c = acc[oi][st];
        c = __builtin_amdgcn_mfma_f32_16x16x32_bf16(a[oi][1], b0, c, 0, 0, 0);
        c = __builtin_amdgcn_mfma_f32_16x16x32_bf16(a[oi][0], b1, c, 0, 0, 0);
        c = __builtin_amdgcn_mfma_f32_16x16x32_bf16(a[oi][0], b0, c, 0, 0, 0);
        acc[oi][st] = c;
      }
    }
  }
}

// ---------------- fused SA: h1 build -> layer2 -> layer3 -> max, via MFMA ----------------
__global__ __launch_bounds__(256, 4) void sa_kernel(
    const float* __restrict__ xc, const float* __restrict__ nxyz,
    const int* __restrict__ bidx, const float* __restrict__ W1f,
    const float* __restrict__ prep, const short* __restrict__ Wf,
    float* __restrict__ feat_out)
{
  __shared__ __align__(16) short hfrag[16384];   // 32KB: 2 splits x 128c x 64s frags
  __shared__ float pcs[512];                     // layer-1 xyz consts {w0,w1,w2,be}*128
  int gb = blockIdx.x, bk = gb >> 7, p = gb & 127;
  int t = threadIdx.x;
  int wave = t >> 6, lane = t & 63;
  int quad = lane >> 4, nl = lane & 15;

  pcs[t] = prep[1280 + t];
  pcs[256 + t] = prep[1536 + t];

  float cen0 = nxyz[(bk * 128 + p) * 3 + 0];
  float cen1 = nxyz[(bk * 128 + p) * 3 + 1];
  float cen2 = nxyz[(bk * 128 + p) * 3 + 2];

  float rmax[2][4] = {{0.f, 0.f, 0.f, 0.f}, {0.f, 0.f, 0.f, 0.f}};
  __syncthreads();

  for (int hh = 0; hh < 2; ++hh) {
    // ---- h1 build: wave w = c-block (kk=w), lane = s within half ----
    {
      int cg = wave;
      int st = lane >> 4, sl = lane & 15;
      int m = bidx[((size_t)gb) * 128 + hh * 64 + lane];
      float g0 = (xc[(bk * 3 + 0) * 1024 + m] - cen0) * (1.0f / 0.15f);
      float g1 = (xc[(bk * 3 + 1) * 1024 + m] - cen1) * (1.0f / 0.15f);
      float g2 = (xc[(bk * 3 + 2) * 1024 + m] - cen2) * (1.0f / 0.15f);
      const float4* wrow = (const float4*)(W1f + ((size_t)(bk * 1024 + m)) * 128 + cg * 32);
      const float4* pcp = (const float4*)pcs + cg * 32;
#pragma unroll
      for (int g = 0; g < 4; ++g) {
        float4 wva = wrow[g * 2], wvb = wrow[g * 2 + 1];
        float wv[8] = {wva.x, wva.y, wva.z, wva.w, wvb.x, wvb.y, wvb.z, wvb.w};
        unsigned sh[8], sm[8];
#pragma unroll
        for (int e = 0; e < 8; ++e) {
          float4 pc = pcp[g * 8 + e];
          float hv = fmaxf(wv[e] + pc.x * g0 + pc.y * g1 + pc.z * g2 + pc.w, 0.f);
          split2rn(hv, sh[e], sm[e]);
        }
        int base = (cg * 4 + st) * 512 + (g * 16 + sl) * 8;
        v4i ph = {(int)(sh[0] | (sh[1] << 16)), (int)(sh[2] | (sh[3] << 16)),
                  (int)(sh[4] | (sh[5] << 16)), (int)(sh[6] | (sh[7] << 16))};
        *(v4i*)&hfrag[base] = ph;
        v4i pm = {(int)(sm[0] | (sm[1] << 16)), (int)(sm[2] | (sm[3] << 16)),
                  (int)(sm[4] | (sm[5] << 16)), (int)(sm[6] | (sm[7] << 16))};
        *(v4i*)&hfrag[base + 8192] = pm;
      }
    }
    __syncthreads();

    // ---- layer 2 (l=0) ----
    f32x4 acc[2][4];
#pragma unroll
    for (int oi = 0; oi < 2; ++oi)
#pragma unroll
      for (int st = 0; st < 4; ++st) acc[oi][st] = (f32x4){0.f, 0.f, 0.f, 0.f};
    mfma_layer(Wf, hfrag, 0, wave, lane, acc);
    __syncthreads();                              // all hfrag reads done

    // ---- h2 epilogue: BN+ReLU, split2, write back as fragments ----
#pragma unroll
    for (int oi = 0; oi < 2; ++oi) {
      int o0 = (wave * 2 + oi) * 16 + quad * 4;
      float4 al = *(const float4*)&prep[256 + o0];
      float4 be = *(const float4*)&prep[384 + o0];
      int kk2 = o0 >> 5, g2 = (o0 & 31) >> 3, j0 = o0 & 7;    // j0 in {0,4}
#pragma unroll
      for (int st = 0; st < 4; ++st) {
        f32x4 cc = acc[oi][st];
        float v0 = fmaxf(fmaf(cc[0], al.x, be.x), 0.f);
        float v1 = fmaxf(fmaf(cc[1], al.y, be.y), 0.f);
        float v2 = fmaxf(fmaf(cc[2], al.z, be.z), 0.f);
        float v3 = fmaxf(fmaf(cc[3], al.w, be.w), 0.f);
        unsigned h0, m0_, h1, m1_, h2, m2_, h3, m3_;
        split2rn(v0, h0, m0_); split2rn(v1, h1, m1_);
        split2rn(v2, h2, m2_); split2rn(v3, h3, m3_);
        int base = (kk2 * 4 + st) * 512 + (g2 * 16 + nl) * 8 + j0;
        v2i w0 = {(int)(h0 | (h1 << 16)), (int)(h2 | (h3 << 16))};
        *(v2i*)&hfrag[base] = w0;
        v2i w1 = {(int)(m0_ | (m1_ << 16)), (int)(m2_ | (m3_ << 16))};
        *(v2i*)&hfrag[base + 8192] = w1;
      }
    }
    __syncthreads();

    // ---- layer 3 (l=1) ----
#pragma unroll
    for (int oi = 0; oi < 2; ++oi)
#pragma unroll
      for (int st = 0; st < 4; ++st) acc[oi][st] = (f32x4){0.f, 0.f, 0.f, 0.f};
    mfma_layer(Wf, hfrag, 1, wave, lane, acc);

    // ---- layer-3 epilogue: BN+ReLU+max over this half's samples ----
#pragma unroll
    for (int oi = 0; oi < 2; ++oi) {
      int o0 = (wave * 2 + oi) * 16 + quad * 4;
      float4 al = *(const float4*)&prep[512 + o0];
      float4 be = *(const float4*)&prep[640 + o0];
#pragma unroll
      for (int st = 0; st < 4; ++st) {
        f32x4 cc = acc[oi][st];
        rmax[oi][0] = fmaxf(rmax[oi][0], fmaxf(fmaf(cc[0], al.x, be.x), 0.f));
        rmax[oi][1] = fmaxf(rmax[oi][1], fmaxf(fmaf(cc[1], al.y, be.y), 0.f));
        rmax[oi][2] = fmaxf(rmax[oi][2], fmaxf(fmaf(cc[2], al.z, be.z), 0.f));
        rmax[oi][3] = fmaxf(rmax[oi][3], fmaxf(fmaf(cc[3], al.w, be.w), 0.f));
      }
    }
    __syncthreads();                              // hfrag reads done before next half
  }

  // ---- reduce max across the 16 s-lanes, write feat ----
#pragma unroll
  for (int oi = 0; oi < 2; ++oi)
#pragma unroll
    for (int r = 0; r < 4; ++r) {
      float v = rmax[oi][r];
      v = fmaxf(v, __shfl_xor(v, 1));
      v = fmaxf(v, __shfl_xor(v, 2));
      v = fmaxf(v, __shfl_xor(v, 4));
      v = fmaxf(v, __shfl_xor(v, 8));
      if (nl == 0) {
        int o = (wave * 2 + oi) * 16 + quad * 4 + r;
        feat_out[(((size_t)bk) << 14) + (o << 7) + p] = v;
      }
    }
}

// 8x8 register-tile GEMM over a 128x128 LDS operand; w is [c][o] in global
__device__ __forceinline__ void gemm_tile(const float* __restrict__ w,
                                          const float* lds, int tx, int ty,
                                          float acc[8][8])
{
#pragma unroll
  for (int i = 0; i < 8; ++i)
#pragma unroll
    for (int j = 0; j < 8; ++j) acc[i][j] = 0.f;
  for (int c = 0; c < 128; ++c) {
    const float4* wr = (const float4*)(w + c * 128 + ty * 8);
    float4 a0 = wr[0], a1 = wr[1];
    const float4* hr = (const float4*)(lds + c * 128 + tx * 8);
    float4 b0 = hr[0], b1 = hr[1];
    float av[8] = {a0.x, a0.y, a0.z, a0.w, a1.x, a1.y, a1.z, a1.w};
    float bv[8] = {b0.x, b0.y, b0.z, b0.w, b1.x, b1.y, b1.z, b1.w};
#pragma unroll
    for (int i = 0; i < 8; ++i)
#pragma unroll
      for (int j = 0; j < 8; ++j) acc[i][j] = fmaf(av[i], bv[j], acc[i][j]);
  }
}

// ---------------- head: c1 -> c2 -> op -> scores ----------------
__global__ __launch_bounds__(256) void head_kernel(const float* __restrict__ featg,
    const float* __restrict__ prep, const float* __restrict__ wt,
    const float* __restrict__ nxyz, const float* __restrict__ opw,
    const float* __restrict__ opb, float* __restrict__ scores)
{
  __shared__ __align__(16) float buf[128 * 128];
  int bk = blockIdx.x, t = threadIdx.x;
  for (int i = t; i < 16384; i += 256) buf[i] = featg[(bk << 14) + i];
  __syncthreads();
  int tx = t & 15, ty = t >> 4;
  float acc[8][8];

  // c1
  gemm_tile(wt, buf, tx, ty, acc);
  __syncthreads();
#pragma unroll
  for (int i = 0; i < 8; ++i) {
    int o = ty * 8 + i;
    float al = prep[768 + o], be = prep[896 + o];
#pragma unroll
    for (int j = 0; j < 8; ++j)
      buf[o * 128 + tx * 8 + j] = fmaxf(fmaf(acc[i][j], al, be), 0.f);
  }
  __syncthreads();

  // c2
  gemm_tile(wt + 16384, buf, tx, ty, acc);
  __syncthreads();
#pragma unroll
  for (int i = 0; i < 8; ++i) {
    int o = ty * 8 + i;
    float al = prep[1024 + o], be = prep[1152 + o];
#pragma unroll
    for (int j = 0; j < 8; ++j)
      buf[o * 128 + tx * 8 + j] = fmaxf(fmaf(acc[i][j], al, be), 0.f);
  }
  __syncthreads();

  // op head + scores assembly
  if (t < 128) {
    int p = t, k = bk % 19;
    float res[5];
#pragma unroll
    for (int j = 0; j < 5; ++j) {
      const float* wr = opw + ((size_t)(k * 5 + j)) * 128;
      float a = opb[k * 5 + j];
      for (int c = 0; c < 128; ++c) a = fmaf(wr[c], buf[c * 128 + p], a);
      res[j] = a;
    }
    float a0 = nxyz[(bk * 128 + p) * 3 + 0];
    float a1 = nxyz[(bk * 128 + p) * 3 + 1];
    float a2 = nxyz[(bk * 128 + p) * 3 + 2];
    float* sc = scores + ((size_t)(bk * 128 + p)) * 5;
    sc[0] = res[0];
    sc[1] = res[1];
    sc[2] = a0 + res[2];
    sc[3] = a1 + res[3];
    sc[4] = a2 + res[4];
  }
}

extern "C" void kernel_launch(void* const* d_in, const int* in_sizes, int n_in,
                              void* d_out, int out_size, void* d_ws, size_t ws_size,
                              hipStream_t stream) {
  (void)in_sizes; (void)n_in; (void)out_size; (void)ws_size;
  const float* xyz  = (const float*)d_in[0];
  const float* fts  = (const float*)d_in[1];
  const float* m1w  = (const float*)d_in[2];
  const float* m1b  = (const float*)d_in[3];
  const float* m1g  = (const float*)d_in[4];
  const float* m1be = (const float*)d_in[5];
  const float* m2w  = (const float*)d_in[6];
  const float* m2b  = (const float*)d_in[7];
  const float* m2g  = (const float*)d_in[8];
  const float* m2be = (const float*)d_in[9];
  const float* m3w  = (const float*)d_in[10];
  const float* m3b  = (const float*)d_in[11];
  const float* m3g  = (const float*)d_in[12];
  const float* m3be = (const float*)d_in[13];
  const float* c1w  = (const float*)d_in[14];
  const float* c1b  = (const float*)d_in[15];
  const float* c1g  = (const float*)d_in[16];
  const float* c1be = (const float*)d_in[17];
  const float* c2w  = (const float*)d_in[18];
  const float* c2b  = (const float*)d_in[19];
  const float* c2g  = (const float*)d_in[20];
  const float* c2be = (const float*)d_in[21];
  const float* opw  = (const float*)d_in[22];
  const float* opb  = (const float*)d_in[23];

  float* out = (float*)d_out;
  char* ws = (char*)d_ws;
  float* xc   = (float*)(ws + OFF_XC);
  float* nxyz = (float*)(ws + OFF_NXYZ);
  int*   bidx = (int*)(ws + OFF_BIDX);
  float* W1f  = (float*)(ws + OFF_W1F);
  float* prep = (float*)(ws + OFF_PREP);
  float* wt   = (float*)(ws + OFF_WT);
  short* Wf   = (short*)(ws + OFF_WF);

  hipLaunchKernelGGL(prep_kernel, dim3(1), dim3(256), 0, stream,
                     m1w, m1g, m1be, m2b, m2g, m2be, m3b, m3g, m3be,
                     c1b, c1g, c1be, c2b, c2g, c2be, prep);
  hipLaunchKernelGGL(wsplit_kernel, dim3(64), dim3(256), 0, stream,
                     m1w, m2w, m3w, c1w, c2w, Wf, wt);
  hipLaunchKernelGGL(fps_kernel, dim3(NBK), dim3(1024), 0, stream,
                     xyz, xc, nxyz, out + OUT_AGG);
  hipLaunchKernelGGL(ball_kernel, dim3(NBK * 128), dim3(64), 0, stream,
                     xc, nxyz, bidx);
  hipLaunchKernelGGL(w1f_kernel, dim3(NBK * 8), dim3(256), 0, stream,
                     fts, m1b, prep, Wf, W1f);
  hipLaunchKernelGGL(sa_kernel, dim3(NBK * 128), dim3(256), 0, stream,
                     xc, nxyz, bidx, W1f, prep, Wf, out + OUT_FEAT);
  hipLaunchKernelGGL(head_kernel, dim3(NBK), dim3(256), 0, stream,
                     out + OUT_FEAT, prep, wt, nxyz, opw, opb, out);
}

// Round 4
// 342.288 us; speedup vs baseline: 2.5683x; 1.4094x over previous
//
#include <hip/hip_runtime.h>
#include <math.h>

// ---------------- problem constants ----------------
// B=2, K=19 -> BK=38 batches; M=1024 points; C=256 feat ch; NPOINT=NSAMPLE=128
#define NBK   38

// ---------------- workspace layout (bytes) ----------------
#define OFF_XC    0u          // [38][3][1024] f32        = 466944
#define OFF_NXYZ  466944u     // [38][128][3]  f32        = 58368
#define OFF_BIDX  525312u     // [38][128][128] i32       = 2490368
#define OFF_W1F   3015680u    // [38][1024][128] f32      = 19922944
#define OFF_PREP  22938624u   // 4096 f32
#define OFF_WT    22955008u   // 32768 f32: c1t (0), c2t (16384)
#define OFF_WF    23086080u   // 131072 shorts: w2/w3 A-frags (0..65535), w1feat A-frags (65536..)
#define OFF_CNT   23348224u   // [38][128] i32 ball counts = 19456

// ---------------- d_out layout (float offsets) ----------------
#define OUT_AGG   24320       // scores at 0: (2,19,128,5)
#define OUT_FEAT  38912       // agg: (2,19,128,3), feat: (2,19,128,128)

typedef short bf16x8 __attribute__((ext_vector_type(8)));   // 8 bf16 = 4 VGPR
typedef float f32x4  __attribute__((ext_vector_type(4)));
typedef int   v4i    __attribute__((ext_vector_type(4)));
typedef int   v2i    __attribute__((ext_vector_type(2)));

// exact IEEE fp32 squared distance, no FMA contraction, ((d0^2+d1^2)+d2^2)
__device__ __forceinline__ float dist2f(float a0, float a1, float a2,
                                        float b0, float b1, float b2) {
#pragma clang fp contract(off)
  float d0 = a0 - b0;
  float d1 = a1 - b1;
  float d2 = a2 - b2;
  return d0 * d0 + d1 * d1 + d2 * d2;
}

// 2-way bf16 split with round-to-nearest-even: v ~= hi + mid, residual <= 2^-18 |v|
// returns the two bf16 bit patterns in the LOW 16 bits of sh/sm.
__device__ __forceinline__ void split2rn(float v, unsigned& sh, unsigned& sm) {
  unsigned u = __float_as_uint(v);
  unsigned rh = (u + 0x7fffu + ((u >> 16) & 1u)) & 0xffff0000u;
  sh = rh >> 16;
  float r1 = v - __uint_as_float(rh);        // exact in fp32
  unsigned u1 = __float_as_uint(r1);
  unsigned rm = (u1 + 0x7fffu + ((u1 >> 16) & 1u)) & 0xffff0000u;
  sm = rm >> 16;
}

// ---------------- prep: fold BN constants ----------------
__global__ __launch_bounds__(256) void prep_kernel(
    const float* __restrict__ m1w, const float* __restrict__ m1g, const float* __restrict__ m1be,
    const float* __restrict__ m2b, const float* __restrict__ m2g, const float* __restrict__ m2be,
    const float* __restrict__ m3b, const float* __restrict__ m3g, const float* __restrict__ m3be,
    const float* __restrict__ c1b, const float* __restrict__ c1g, const float* __restrict__ c1be,
    const float* __restrict__ c2b, const float* __restrict__ c2g, const float* __restrict__ c2be,
    float* __restrict__ prep)
{
  int t = threadIdx.x;
  if (t < 128) {
    float inv = 1.0f / sqrtf(1.0f + 1e-5f);
    float a1 = m1g[t] * inv;
    prep[t] = a1;                      // alpha1 (used by w1f epilogue)
    float a2 = m2g[t] * inv;  prep[256 + t] = a2;  prep[384 + t] = fmaf(m2b[t], a2, m2be[t]);
    float a3 = m3g[t] * inv;  prep[512 + t] = a3;  prep[640 + t] = fmaf(m3b[t], a3, m3be[t]);
    float ac1 = c1g[t] * inv; prep[768 + t] = ac1; prep[896 + t] = fmaf(c1b[t], ac1, c1be[t]);
    float ac2 = c2g[t] * inv; prep[1024 + t] = ac2; prep[1152 + t] = fmaf(c2b[t], ac2, c2be[t]);
    // packed per-channel consts for h1 build: {wx0*a1, wx1*a1, wx2*a1, be1}
    prep[1280 + 4 * t + 0] = m1w[t * 259 + 0] * a1;
    prep[1280 + 4 * t + 1] = m1w[t * 259 + 1] * a1;
    prep[1280 + 4 * t + 2] = m1w[t * 259 + 2] * a1;
    prep[1280 + 4 * t + 3] = m1be[t];
  }
}

// ---------------- wsplit: pre-split weights into MFMA A-fragment layout ----------
// A-frag block of 512 shorts, index (q*16 + m-in-tile)*8 + j; read as lane*8+j.
// w2/w3: Wf[((l*2+sp)*4+kk)*8+ot]. w1feat: Wf+65536, [(sp*8+kk)*8+ot].
// Also emits c1t/c2t transposes for head_kernel.
__global__ __launch_bounds__(256) void wsplit_kernel(
    const float* __restrict__ m1w, const float* __restrict__ m2w,
    const float* __restrict__ m3w, const float* __restrict__ c1w,
    const float* __restrict__ c2w, short* __restrict__ Wf, float* __restrict__ wt)
{
  int idx = blockIdx.x * 256 + threadIdx.x;      // 0..16383 (64 blocks)
#pragma unroll
  for (int e = 0; e < 4; ++e) {
    int i = idx * 4 + e;                         // 0..65535
    if (i < 32768) {
      int c = i & 127, o = (i >> 7) & 127, l = i >> 14;
      float w = (l ? m3w : m2w)[o * 128 + c];
      unsigned sh, sm;
      split2rn(w, sh, sm);
      int ot = o >> 4, mm = o & 15, kk = c >> 5, q = (c & 31) >> 3, j = c & 7;
      int within = (q * 16 + mm) * 8 + j;
      Wf[(((l * 2 + 0) * 4 + kk) * 8 + ot) * 512 + within] = (short)sh;
      Wf[(((l * 2 + 1) * 4 + kk) * 8 + ot) * 512 + within] = (short)sm;
    } else {
      int jdx = i - 32768;
      int o = jdx >> 8, c = jdx & 255;
      float w = m1w[o * 259 + 3 + c];
      unsigned sh, sm;
      split2rn(w, sh, sm);
      int ot = o >> 4, mm = o & 15, kk = c >> 5, q = (c & 31) >> 3, j = c & 7;
      int within = (q * 16 + mm) * 8 + j;
      Wf[65536 + ((kk) * 8 + ot) * 512 + within] = (short)sh;
      Wf[65536 + ((8 + kk) * 8 + ot) * 512 + within] = (short)sm;
    }
  }
  {
    int i = idx;                                  // 0..16383, exactly one pass
    int c = i >> 7, o = i & 127;
    wt[i] = c1w[o * 128 + c];                     // c1t[c][o]
    wt[16384 + i] = c2w[o * 128 + c];             // c2t[c][o]
  }
}

// ---------------- FPS: 256 threads/batch, 4 pts/lane in regs, 1 barrier/iter ----
__global__ __launch_bounds__(256) void fps_kernel(const float* __restrict__ xyz,
    float* __restrict__ xc, float* __restrict__ nxyz, float* __restrict__ agg)
{
  int bk = blockIdx.x, t = threadIdx.x;
  int b = bk / 19, k = bk % 19;
  int wave = t >> 6, lane = t & 63;
  __shared__ float sx0[1024], sx1[1024], sx2[1024];
  __shared__ unsigned long long skey[8];          // [it&1][wave]
  float x0[4], x1[4], x2[4], dist[4];
#pragma unroll
  for (int j = 0; j < 4; ++j) {
    int i = j * 256 + t;
    const float* src = xyz + ((size_t)((b * 1024 + i) * 19 + k)) * 3;
    x0[j] = src[0]; x1[j] = src[1]; x2[j] = src[2];
    sx0[i] = x0[j]; sx1[i] = x1[j]; sx2[i] = x2[j];
    xc[(bk * 3 + 0) * 1024 + i] = x0[j];
    xc[(bk * 3 + 1) * 1024 + i] = x1[j];
    xc[(bk * 3 + 2) * 1024 + i] = x2[j];
    dist[j] = 1e10f;
  }
  int far = 0;
  __syncthreads();
  for (int it = 0; it < 128; ++it) {
    float c0 = sx0[far], c1 = sx1[far], c2 = sx2[far];
    if (t < 3) {
      float cv = (t == 0) ? c0 : ((t == 1) ? c1 : c2);
      nxyz[(bk * 128 + it) * 3 + t] = cv;
      agg[(bk * 128 + it) * 3 + t]  = cv;
    }
    unsigned long long best = 0ull;
#pragma unroll
    for (int j = 0; j < 4; ++j) {
      int i = j * 256 + t;
      float d = dist2f(x0[j], x1[j], x2[j], c0, c1, c2);
      float dj = fminf(dist[j], d);
      dist[j] = dj;
      // max dist wins; ties -> smallest index (matches jnp.argmax first-max)
      unsigned long long key =
          ((unsigned long long)__float_as_uint(dj) << 32) | (unsigned)(1023 - i);
      if (key > best) best = key;
    }
#pragma unroll
    for (int off = 32; off > 0; off >>= 1) {
      unsigned hi = (unsigned)(best >> 32), lo = (unsigned)best;
      unsigned h2 = __shfl_xor(hi, off);
      unsigned l2 = __shfl_xor(lo, off);
      unsigned long long ob = ((unsigned long long)h2 << 32) | l2;
      if (ob > best) best = ob;
    }
    if (lane == 0) skey[(it & 1) * 4 + wave] = best;
    __syncthreads();
    unsigned long long bb = skey[(it & 1) * 4 + (lane & 3)];
#pragma unroll
    for (int off = 1; off <= 2; off <<= 1) {
      unsigned hi = (unsigned)(bb >> 32), lo = (unsigned)bb;
      unsigned h2 = __shfl_xor(hi, off);
      unsigned l2 = __shfl_xor(lo, off);
      unsigned long long ob = ((unsigned long long)h2 << 32) | l2;
      if (ob > bb) bb = ob;
    }
    far = 1023 - (int)(bb & 0xffffffffu);
  }
}

// ---------------- ball query: one wave per (bk,p); also emits count ------------
__global__ __launch_bounds__(64) void ball_kernel(const float* __restrict__ xc,
    const float* __restrict__ nxyz, int* __restrict__ bidx, int* __restrict__ counts)
{
  int gb = blockIdx.x;
  int bk = gb >> 7, p = gb & 127, lane = threadIdx.x;
  const float* x0 = xc + (bk * 3 + 0) * 1024;
  const float* x1 = xc + (bk * 3 + 1) * 1024;
  const float* x2 = xc + (bk * 3 + 2) * 1024;
  float c0 = nxyz[(bk * 128 + p) * 3 + 0];
  float c1 = nxyz[(bk * 128 + p) * 3 + 1];
  float c2 = nxyz[(bk * 128 + p) * 3 + 2];
  int* out = bidx + ((size_t)gb) * 128;
  int count = 0, first = 0;
  bool got = false;
  for (int ch = 0; ch < 16 && count < 128; ++ch) {
    int m = (ch << 6) + lane;
    float d = dist2f(x0[m], x1[m], x2[m], c0, c1, c2);
    bool flag = d < 0.0225f;                 // strict fp32 compare, RADIUS^2
    unsigned long long mask = __ballot(flag);
    if (!got && mask) { first = (ch << 6) + __builtin_ctzll(mask); got = true; }
    int pos = count + (int)__popcll(mask & ((1ull << lane) - 1ull));
    if (flag && pos < 128) out[pos] = m;
    count += (int)__popcll(mask);
  }
  for (int j = count + lane; j < 128; j += 64) out[j] = first;
  if (lane == 0) counts[gb] = count > 128 ? 128 : count;
}

// ---------------- W1f: per-bk layer-1 feature GEMM via split2 MFMA ----------------
// W1f[bk][m][o] = (sum_c w1[o][3+c] * f[bk][c][m] + b1[o]) * alpha1[o]
__global__ __launch_bounds__(256, 2) void w1f_kernel(
    const float* __restrict__ feats, const float* __restrict__ m1b,
    const float* __restrict__ prep, const short* __restrict__ Wf,
    float* __restrict__ W1f)
{
  __shared__ __align__(16) short ffrag[16384];    // 32KB: [sp2][kkl2][st8]*512
  int blk = blockIdx.x;
  int bk = blk >> 3, m0 = (blk & 7) << 7;
  int b = bk / 19, k = bk % 19;
  int t = threadIdx.x;
  int wave = t >> 6, lane = t & 63;
  int quad = lane >> 4, nl = lane & 15;
  int mloc = t & 127, chalf = t >> 7;
  int st_w = mloc >> 4, sl_w = mloc & 15;
  const float* fbase = feats + ((size_t)(b * 4864 + k)) * 1024 + m0 + mloc;
  const short* WA = Wf + 65536;

  f32x4 acc[2][8];
#pragma unroll
  for (int oi = 0; oi < 2; ++oi)
#pragma unroll
    for (int st = 0; st < 8; ++st) acc[oi][st] = (f32x4){0.f, 0.f, 0.f, 0.f};

  for (int ch = 0; ch < 4; ++ch) {
    int cbase = ch * 64 + chalf * 32;
    // ---- stage 64 channels x 128 m as split2 B-frags ----
#pragma unroll
    for (int g = 0; g < 4; ++g) {
      float v[8];
#pragma unroll
      for (int j = 0; j < 8; ++j)
        v[j] = fbase[(size_t)(cbase + g * 8 + j) * 19456];
      unsigned sh[8], sm[8];
#pragma unroll
      for (int j = 0; j < 8; ++j) split2rn(v[j], sh[j], sm[j]);
      int base = chalf * 4096 + st_w * 512 + (g * 16 + sl_w) * 8;
      v4i ph = {(int)(sh[0] | (sh[1] << 16)), (int)(sh[2] | (sh[3] << 16)),
                (int)(sh[4] | (sh[5] << 16)), (int)(sh[6] | (sh[7] << 16))};
      *(v4i*)&ffrag[base] = ph;
      v4i pm = {(int)(sm[0] | (sm[1] << 16)), (int)(sm[2] | (sm[3] << 16)),
                (int)(sm[4] | (sm[5] << 16)), (int)(sm[6] | (sm[7] << 16))};
      *(v4i*)&ffrag[base + 8192] = pm;
    }
    __syncthreads();
    // ---- MFMA over the 2 kk groups of this chunk ----
#pragma unroll
    for (int kkl = 0; kkl < 2; ++kkl) {
      int kk = ch * 2 + kkl;
      bf16x8 a[2][2];
#pragma unroll
      for (int oi = 0; oi < 2; ++oi)
#pragma unroll
        for (int sp = 0; sp < 2; ++sp)
          a[oi][sp] = *(const bf16x8*)(WA + ((sp * 8 + kk) * 8 + wave * 2 + oi) * 512 + lane * 8);
#pragma unroll
      for (int st = 0; st < 8; ++st) {
        const short* hb = ffrag + kkl * 4096 + st * 512 + lane * 8;
        bf16x8 b0 = *(const bf16x8*)hb;
        bf16x8 b1 = *(const bf16x8*)(hb + 8192);
#pragma unroll
        for (int oi = 0; oi < 2; ++oi) {
          f32x4 c = acc[oi][st];
          c = __builtin_amdgcn_mfma_f32_16x16x32_bf16(a[oi][1], b0, c, 0, 0, 0);
          c = __builtin_amdgcn_mfma_f32_16x16x32_bf16(a[oi][0], b1, c, 0, 0, 0);
          c = __builtin_amdgcn_mfma_f32_16x16x32_bf16(a[oi][0], b0, c, 0, 0, 0);
          acc[oi][st] = c;
        }
      }
    }
    __syncthreads();
  }
  // ---- epilogue: (acc + b) * alpha, store ----
#pragma unroll
  for (int oi = 0; oi < 2; ++oi) {
    int o0 = (wave * 2 + oi) * 16 + quad * 4;
    float4 bb = *(const float4*)&m1b[o0];
    float4 al = *(const float4*)&prep[o0];
#pragma unroll
    for (int st = 0; st < 8; ++st) {
      int m_out = m0 + st * 16 + nl;
      f32x4 cc = acc[oi][st];
      float4 r;
      r.x = (cc[0] + bb.x) * al.x;
      r.y = (cc[1] + bb.y) * al.y;
      r.z = (cc[2] + bb.z) * al.z;
      r.w = (cc[3] + bb.w) * al.w;
      *(float4*)&W1f[((size_t)(bk * 1024 + m_out)) * 128 + o0] = r;
    }
  }
}

// ---------------- MFMA GEMM over one 128(c) x nst_h*16(s) fragment buffer ----------
// hfrag: [sp 2][kk 4][st 4] blocks of 512 shorts (lane*8 + j), sp stride 8192.
__device__ __forceinline__ void mfma_layer(const short* __restrict__ Wf,
                                           const short* hfrag, int l,
                                           int wave, int lane, int nst_h,
                                           f32x4 acc[2][4])
{
#pragma unroll 1
  for (int kk = 0; kk < 4; ++kk) {
    bf16x8 a[2][2];
#pragma unroll
    for (int oi = 0; oi < 2; ++oi)
#pragma unroll
      for (int sp = 0; sp < 2; ++sp)
        a[oi][sp] = *(const bf16x8*)(Wf + (((l * 2 + sp) * 4 + kk) * 8 + (wave * 2 + oi)) * 512 + lane * 8);
    for (int st = 0; st < nst_h; ++st) {
      const short* hb = hfrag + kk * 2048 + st * 512 + lane * 8;
      bf16x8 b0 = *(const bf16x8*)(hb);           // hi
      bf16x8 b1 = *(const bf16x8*)(hb + 8192);    // mid
#pragma unroll
      for (int oi = 0; oi < 2; ++oi) {
        f32x4 c = acc[oi][st];
        c = __builtin_amdgcn_mfma_f32_16x16x32_bf16(a[oi][1], b0, c, 0, 0, 0);
        c = __builtin_amdgcn_mfma_f32_16x16x32_bf16(a[oi][0], b1, c, 0, 0, 0);
        c = __builtin_amdgcn_mfma_f32_16x16x32_bf16(a[oi][0], b0, c, 0, 0, 0);
        acc[oi][st] = c;
      }
    }
  }
}

// ---------------- fused SA: h1 build -> layer2 -> layer3 -> max, via MFMA ----------
// Only ceil(count/16) sample tiles are processed: padded slots in bidx replicate
// the ball's first in-radius point (a real sample), so the max is unchanged.
__global__ __launch_bounds__(256, 4) void sa_kernel(
    const float* __restrict__ xc, const float* __restrict__ nxyz,
    const int* __restrict__ bidx, const int* __restrict__ counts,
    const float* __restrict__ W1f, const float* __restrict__ prep,
    const short* __restrict__ Wf, float* __restrict__ feat_out)
{
  __shared__ __align__(16) short hfrag[16384];   // 32KB: 2 splits x 128c x 64s frags
  __shared__ float pcs[512];                     // layer-1 xyz consts {w0,w1,w2,be}*128
  int gb = blockIdx.x, bk = gb >> 7, p = gb & 127;
  int t = threadIdx.x;
  int wave = t >> 6, lane = t & 63;
  int quad = lane >> 4, nl = lane & 15;

  pcs[t] = prep[1280 + t];
  pcs[256 + t] = prep[1536 + t];

  int scount = counts[gb];
  int nst = (scount + 15) >> 4;                  // 1..8 sample tiles (16 samples each)

  float cen0 = nxyz[(bk * 128 + p) * 3 + 0];
  float cen1 = nxyz[(bk * 128 + p) * 3 + 1];
  float cen2 = nxyz[(bk * 128 + p) * 3 + 2];

  float rmax[2][4] = {{0.f, 0.f, 0.f, 0.f}, {0.f, 0.f, 0.f, 0.f}};
  __syncthreads();

  for (int hh = 0; hh < 2; ++hh) {
    int nst_h = nst - hh * 4;
    if (nst_h <= 0) break;
    if (nst_h > 4) nst_h = 4;
    // ---- h1 build: wave w = c-block (kk=w), lane = s within half ----
    {
      int cg = wave;
      int st = lane >> 4, sl = lane & 15;
      if (st < nst_h) {
        int m = bidx[((size_t)gb) * 128 + hh * 64 + lane];
        float g0 = (xc[(bk * 3 + 0) * 1024 + m] - cen0) * (1.0f / 0.15f);
        float g1 = (xc[(bk * 3 + 1) * 1024 + m] - cen1) * (1.0f / 0.15f);
        float g2 = (xc[(bk * 3 + 2) * 1024 + m] - cen2) * (1.0f / 0.15f);
        const float4* wrow = (const float4*)(W1f + ((size_t)(bk * 1024 + m)) * 128 + cg * 32);
        const float4* pcp = (const float4*)pcs + cg * 32;
#pragma unroll
        for (int g = 0; g < 4; ++g) {
          float4 wva = wrow[g * 2], wvb = wrow[g * 2 + 1];
          float wv[8] = {wva.x, wva.y, wva.z, wva.w, wvb.x, wvb.y, wvb.z, wvb.w};
          unsigned sh[8], sm[8];
#pragma unroll
          for (int e = 0; e < 8; ++e) {
            float4 pc = pcp[g * 8 + e];
            float hv = fmaxf(wv[e] + pc.x * g0 + pc.y * g1 + pc.z * g2 + pc.w, 0.f);
            split2rn(hv, sh[e], sm[e]);
          }
          int base = (cg * 4 + st) * 512 + (g * 16 + sl) * 8;
          v4i ph = {(int)(sh[0] | (sh[1] << 16)), (int)(sh[2] | (sh[3] << 16)),
                    (int)(sh[4] | (sh[5] << 16)), (int)(sh[6] | (sh[7] << 16))};
          *(v4i*)&hfrag[base] = ph;
          v4i pm = {(int)(sm[0] | (sm[1] << 16)), (int)(sm[2] | (sm[3] << 16)),
                    (int)(sm[4] | (sm[5] << 16)), (int)(sm[6] | (sm[7] << 16))};
          *(v4i*)&hfrag[base + 8192] = pm;
        }
      }
    }
    __syncthreads();

    // ---- layer 2 (l=0) ----
    f32x4 acc[2][4];
#pragma unroll
    for (int oi = 0; oi < 2; ++oi)
#pragma unroll
      for (int st = 0; st < 4; ++st) acc[oi][st] = (f32x4){0.f, 0.f, 0.f, 0.f};
    mfma_layer(Wf, hfrag, 0, wave, lane, nst_h, acc);
    __syncthreads();                              // all hfrag reads done

    // ---- h2 epilogue: BN+ReLU, split2, write back as fragments ----
#pragma unroll
    for (int oi = 0; oi < 2; ++oi) {
      int o0 = (wave * 2 + oi) * 16 + quad * 4;
      float4 al = *(const float4*)&prep[256 + o0];
      float4 be = *(const float4*)&prep[384 + o0];
      int kk2 = o0 >> 5, g2 = (o0 & 31) >> 3, j0 = o0 & 7;    // j0 in {0,4}
      for (int st = 0; st < nst_h; ++st) {
        f32x4 cc = acc[oi][st];
        float v0 = fmaxf(fmaf(cc[0], al.x, be.x), 0.f);
        float v1 = fmaxf(fmaf(cc[1], al.y, be.y), 0.f);
        float v2 = fmaxf(fmaf(cc[2], al.z, be.z), 0.f);
        float v3 = fmaxf(fmaf(cc[3], al.w, be.w), 0.f);
        unsigned h0, m0_, h1, m1_, h2, m2_, h3, m3_;
        split2rn(v0, h0, m0_); split2rn(v1, h1, m1_);
        split2rn(v2, h2, m2_); split2rn(v3, h3, m3_);
        int base = (kk2 * 4 + st) * 512 + (g2 * 16 + nl) * 8 + j0;
        v2i w0 = {(int)(h0 | (h1 << 16)), (int)(h2 | (h3 << 16))};
        *(v2i*)&hfrag[base] = w0;
        v2i w1 = {(int)(m0_ | (m1_ << 16)), (int)(m2_ | (m3_ << 16))};
        *(v2i*)&hfrag[base + 8192] = w1;
      }
    }
    __syncthreads();

    // ---- layer 3 (l=1) ----
#pragma unroll
    for (int oi = 0; oi < 2; ++oi)
#pragma unroll
      for (int st = 0; st < 4; ++st) acc[oi][st] = (f32x4){0.f, 0.f, 0.f, 0.f};
    mfma_layer(Wf, hfrag, 1, wave, lane, nst_h, acc);

    // ---- layer-3 epilogue: BN+ReLU+max over this half's processed tiles ----
#pragma unroll
    for (int oi = 0; oi < 2; ++oi) {
      int o0 = (wave * 2 + oi) * 16 + quad * 4;
      float4 al = *(const float4*)&prep[512 + o0];
      float4 be = *(const float4*)&prep[640 + o0];
      for (int st = 0; st < nst_h; ++st) {        // guard: untouched acc tiles are 0
        f32x4 cc = acc[oi][st];
        rmax[oi][0] = fmaxf(rmax[oi][0], fmaxf(fmaf(cc[0], al.x, be.x), 0.f));
        rmax[oi][1] = fmaxf(rmax[oi][1], fmaxf(fmaf(cc[1], al.y, be.y), 0.f));
        rmax[oi][2] = fmaxf(rmax[oi][2], fmaxf(fmaf(cc[2], al.z, be.z), 0.f));
        rmax[oi][3] = fmaxf(rmax[oi][3], fmaxf(fmaf(cc[3], al.w, be.w), 0.f));
      }
    }
    __syncthreads();                              // hfrag reads done before next half
  }

  // ---- reduce max across the 16 s-lanes, write feat ----
#pragma unroll
  for (int oi = 0; oi < 2; ++oi)
#pragma unroll
    for (int r = 0; r < 4; ++r) {
      float v = rmax[oi][r];
      v = fmaxf(v, __shfl_xor(v, 1));
      v = fmaxf(v, __shfl_xor(v, 2));
      v = fmaxf(v, __shfl_xor(v, 4));
      v = fmaxf(v, __shfl_xor(v, 8));
      if (nl == 0) {
        int o = (wave * 2 + oi) * 16 + quad * 4 + r;
        feat_out[(((size_t)bk) << 14) + (o << 7) + p] = v;
      }
    }
}

// 8x8 register-tile GEMM over a 128x128 LDS operand; w is [c][o] in global
__device__ __forceinline__ void gemm_tile(const float* __restrict__ w,
                                          const float* lds, int tx, int ty,
                                          float acc[8][8])
{
#pragma unroll
  for (int i = 0; i < 8; ++i)
#pragma unroll
    for (int j = 0; j < 8; ++j) acc[i][j] = 0.f;
  for (int c = 0; c < 128; ++c) {
    const float4* wr = (const float4*)(w + c * 128 + ty * 8);
    float4 a0 = wr[0], a1 = wr[1];
    const float4* hr = (const float4*)(lds + c * 128 + tx * 8);
    float4 b0 = hr[0], b1 = hr[1];
    float av[8] = {a0.x, a0.y, a0.z, a0.w, a1.x, a1.y, a1.z, a1.w};
    float bv[8] = {b0.x, b0.y, b0.z, b0.w, b1.x, b1.y, b1.z, b1.w};
#pragma unroll
    for (int i = 0; i < 8; ++i)
#pragma unroll
      for (int j = 0; j < 8; ++j) acc[i][j] = fmaf(av[i], bv[j], acc[i][j]);
  }
}

// ---------------- head: c1 -> c2 -> op -> scores ----------------
__global__ __launch_bounds__(256) void head_kernel(const float* __restrict__ featg,
    const float* __restrict__ prep, const float* __restrict__ wt,
    const float* __restrict__ nxyz, const float* __restrict__ opw,
    const float* __restrict__ opb, float* __restrict__ scores)
{
  __shared__ __align__(16) float buf[128 * 128];
  int bk = blockIdx.x, t = threadIdx.x;
  for (int i = t; i < 16384; i += 256) buf[i] = featg[(bk << 14) + i];
  __syncthreads();
  int tx = t & 15, ty = t >> 4;
  float acc[8][8];

  // c1
  gemm_tile(wt, buf, tx, ty, acc);
  __syncthreads();
#pragma unroll
  for (int i = 0; i < 8; ++i) {
    int o = ty * 8 + i;
    float al = prep[768 + o], be = prep[896 + o];
#pragma unroll
    for (int j = 0; j < 8; ++j)
      buf[o * 128 + tx * 8 + j] = fmaxf(fmaf(acc[i][j], al, be), 0.f);
  }
  __syncthreads();

  // c2
  gemm_tile(wt + 16384, buf, tx, ty, acc);
  __syncthreads();
#pragma unroll
  for (int i = 0; i < 8; ++i) {
    int o = ty * 8 + i;
    float al = prep[1024 + o], be = prep[1152 + o];
#pragma unroll
    for (int j = 0; j < 8; ++j)
      buf[o * 128 + tx * 8 + j] = fmaxf(fmaf(acc[i][j], al, be), 0.f);
  }
  __syncthreads();

  // op head + scores assembly
  if (t < 128) {
    int p = t, k = bk % 19;
    float res[5];
#pragma unroll
    for (int j = 0; j < 5; ++j) {
      const float* wr = opw + ((size_t)(k * 5 + j)) * 128;
      float a = opb[k * 5 + j];
      for (int c = 0; c < 128; ++c) a = fmaf(wr[c], buf[c * 128 + p], a);
      res[j] = a;
    }
    float a0 = nxyz[(bk * 128 + p) * 3 + 0];
    float a1 = nxyz[(bk * 128 + p) * 3 + 1];
    float a2 = nxyz[(bk * 128 + p) * 3 + 2];
    float* sc = scores + ((size_t)(bk * 128 + p)) * 5;
    sc[0] = res[0];
    sc[1] = res[1];
    sc[2] = a0 + res[2];
    sc[3] = a1 + res[3];
    sc[4] = a2 + res[4];
  }
}

extern "C" void kernel_launch(void* const* d_in, const int* in_sizes, int n_in,
                              void* d_out, int out_size, void* d_ws, size_t ws_size,
                              hipStream_t stream) {
  (void)in_sizes; (void)n_in; (void)out_size; (void)ws_size;
  const float* xyz  = (const float*)d_in[0];
  const float* fts  = (const float*)d_in[1];
  const float* m1w  = (const float*)d_in[2];
  const float* m1b  = (const float*)d_in[3];
  const float* m1g  = (const float*)d_in[4];
  const float* m1be = (const float*)d_in[5];
  const float* m2w  = (const float*)d_in[6];
  const float* m2b  = (const float*)d_in[7];
  const float* m2g  = (const float*)d_in[8];
  const float* m2be = (const float*)d_in[9];
  const float* m3w  = (const float*)d_in[10];
  const float* m3b  = (const float*)d_in[11];
  const float* m3g  = (const float*)d_in[12];
  const float* m3be = (const float*)d_in[13];
  const float* c1w  = (const float*)d_in[14];
  const float* c1b  = (const float*)d_in[15];
  const float* c1g  = (const float*)d_in[16];
  const float* c1be = (const float*)d_in[17];
  const float* c2w  = (const float*)d_in[18];
  const float* c2b  = (const float*)d_in[19];
  const float* c2g  = (const float*)d_in[20];
  const float* c2be = (const float*)d_in[21];
  const float* opw  = (const float*)d_in[22];
  const float* opb  = (const float*)d_in[23];

  float* out = (float*)d_out;
  char* ws = (char*)d_ws;
  float* xc   = (float*)(ws + OFF_XC);
  float* nxyz = (float*)(ws + OFF_NXYZ);
  int*   bidx = (int*)(ws + OFF_BIDX);
  float* W1f  = (float*)(ws + OFF_W1F);
  float* prep = (float*)(ws + OFF_PREP);
  float* wt   = (float*)(ws + OFF_WT);
  short* Wf   = (short*)(ws + OFF_WF);
  int*   cnt  = (int*)(ws + OFF_CNT);

  hipLaunchKernelGGL(prep_kernel, dim3(1), dim3(256), 0, stream,
                     m1w, m1g, m1be, m2b, m2g, m2be, m3b, m3g, m3be,
                     c1b, c1g, c1be, c2b, c2g, c2be, prep);
  hipLaunchKernelGGL(wsplit_kernel, dim3(64), dim3(256), 0, stream,
                     m1w, m2w, m3w, c1w, c2w, Wf, wt);
  hipLaunchKernelGGL(fps_kernel, dim3(NBK), dim3(256), 0, stream,
                     xyz, xc, nxyz, out + OUT_AGG);
  hipLaunchKernelGGL(ball_kernel, dim3(NBK * 128), dim3(64), 0, stream,
                     xc, nxyz, bidx, cnt);
  hipLaunchKernelGGL(w1f_kernel, dim3(NBK * 8), dim3(256), 0, stream,
                     fts, m1b, prep, Wf, W1f);
  hipLaunchKernelGGL(sa_kernel, dim3(NBK * 128), dim3(256), 0, stream,
                     xc, nxyz, bidx, cnt, W1f, prep, Wf, out + OUT_FEAT);
  hipLaunchKernelGGL(head_kernel, dim3(NBK), dim3(256), 0, stream,
                     out + OUT_FEAT, prep, wt, nxyz, opw, opb, out);
}